// Round 6
// baseline (328.547 us; speedup 1.0000x reference)
//
#include <hip/hip_runtime.h>

// DynamicMemoryCell: B=8, N=2048, IN=256, MEM=256, CTX=128
// out0 = new_memory [8,2048,256] f32 ; out1 = attention_probs [8,2048,2048] f32
// Wv/value/context dead in reference -> skipped.
//
// R5: all kernels 512-thr / >=2 blocks/CU / ~4 waves/SIMD.
//  k1: Q/K projection, split-fp16 (hi/lo), 8 waves x 16 cols, A staged 16-row chunks.
//  k2ru: r+u gates fused via wave groups (0-3 r, 4-7 u) sharing A-staging.
//  k2c: candidate + combine.
//  k3: swapped-operand MFMA (rows=keys) -> float4-coalesced prob stores,
//      fp16 numerators exp(s-14) in 32 VGPR, batch->XCD grid.

typedef _Float16 half8 __attribute__((ext_vector_type(8)));
typedef _Float16 half4 __attribute__((ext_vector_type(4)));
typedef float floatx4 __attribute__((ext_vector_type(4)));

#define MFMA16(a, b, c) __builtin_amdgcn_mfma_f32_16x16x32_f16((a), (b), (c), 0, 0, 0)

// ws layout (units: _Float16)
#define OFF_WQH 0
#define OFF_WQL 32768
#define OFF_WKH 65536
#define OFF_WKL 98304
#define OFF_WUH 131072
#define OFF_WRH 262144
#define OFF_WCH 393216
#define OFF_Q   524288
#define OFF_K   2621440
// total 4718592 halves = 9,437,184 bytes

// ---------------------------------------------------------------- K0: weights fp32 -> fp16 (hi/lo for Wq/Wk)
__global__ __launch_bounds__(256) void k0_convert(
    const float* __restrict__ Wq, const float* __restrict__ Wk,
    const float* __restrict__ Wu, const float* __restrict__ Wr,
    const float* __restrict__ Wc, _Float16* __restrict__ ws)
{
  int i = blockIdx.x * 256 + threadIdx.x;
  if (i < 32768) {
    float w = Wq[i];
    _Float16 h = (_Float16)w;
    ws[OFF_WQH + i] = h;
    ws[OFF_WQL + i] = (_Float16)(w - (float)h);
  } else if (i < 65536) {
    int j = i - 32768;
    float w = Wk[j];
    _Float16 h = (_Float16)w;
    ws[OFF_WKH + j] = h;
    ws[OFF_WKL + j] = (_Float16)(w - (float)h);
  } else {
    int j = i - 65536;
    if (j < 131072)      ws[OFF_WUH + j]            = (_Float16)Wu[j];
    else if (j < 262144) ws[OFF_WRH + (j - 131072)] = (_Float16)Wr[j - 131072];
    else                 ws[OFF_WCH + (j - 262144)] = (_Float16)Wc[j - 262144];
  }
}

// ---------------------------------------------------------------- K1: Q/K projection (split-fp16, 3 products)
// grid (256, 2) x 512. x: 64-row block, y: 0=Q(input,Wq) 1=K(prev,Wk).
// 8 waves x 16 cols (all 128 cols). A hi/lo staged in 16-row chunks (2x16 KB LDS).
__global__ __launch_bounds__(512) void k1_proj(
    const float* __restrict__ input, const float* __restrict__ prev,
    const float* __restrict__ bq, const float* __restrict__ bk,
    _Float16* __restrict__ ws)
{
  __shared__ char smem[2 * 16384];   // 16 rows x [hi 512B | lo 512B]
  const int which = blockIdx.y;
  const float* x = which ? prev : input;
  const _Float16* WH = ws + (which ? OFF_WKH : OFF_WQH);
  const _Float16* WL = ws + (which ? OFF_WKL : OFF_WQL);
  const float* bias = which ? bk : bq;
  _Float16* out = ws + (which ? OFF_K : OFF_Q);

  const int tid = threadIdx.x, w = tid >> 6, l = tid & 63;
  const int lr = l & 15, lg = l >> 4;
  const int rows0 = blockIdx.x * 64;
  const int c = w * 16 + lr;

  half8 bh[8], blo[8];
#pragma unroll
  for (int ks = 0; ks < 8; ++ks) {
    bh[ks]  = *(const half8*)(WH + (size_t)c * 256 + ks * 32 + lg * 8);
    blo[ks] = *(const half8*)(WL + (size_t)c * 256 + ks * 32 + lg * 8);
  }
  const float bv = bias[c];

  const int srow = tid >> 5, scol = (tid & 31) * 8;
  const int ssz = (srow & 7) << 4;
  floatx4 st0, st1;

#define K1_LOAD(ch) { const float* src = x + ((size_t)rows0 + (ch) * 16 + srow) * 256 + scol; \
  st0 = *(const floatx4*)src; st1 = *(const floatx4*)(src + 4); }
#define K1_WRITE(ch) { char* bufw = smem + ((ch) & 1) * 16384; \
  half8 h, lo; \
  _Pragma("unroll") for (int j = 0; j < 4; ++j) { \
    h[j] = (_Float16)st0[j]; lo[j] = (_Float16)(st0[j] - (float)h[j]); \
    h[4+j] = (_Float16)st1[j]; lo[4+j] = (_Float16)(st1[j] - (float)h[4+j]); } \
  int o = srow * 1024 + ((scol * 2) ^ ssz); \
  *(half8*)(bufw + o) = h; *(half8*)(bufw + o + 512) = lo; }

  K1_LOAD(0); K1_WRITE(0);
  __syncthreads();
#pragma unroll 1
  for (int ch = 0; ch < 4; ++ch) {
    if (ch < 3) K1_LOAD(ch + 1);
    const char* buf = smem + (ch & 1) * 16384;
    floatx4 acc = {0.f, 0.f, 0.f, 0.f};
    const int base = lr * 1024, sz = (lr & 7) << 4;
#pragma unroll
    for (int ks = 0; ks < 8; ++ks) {
      int o = base + ((ks * 64 + lg * 16) ^ sz);
      half8 ah = *(const half8*)(buf + o);
      half8 al = *(const half8*)(buf + o + 512);
      acc = MFMA16(ah, bh[ks], acc);
      acc = MFMA16(al, bh[ks], acc);
      acc = MFMA16(ah, blo[ks], acc);
    }
#pragma unroll
    for (int j = 0; j < 4; ++j)
      out[((size_t)rows0 + ch * 16 + lg * 4 + j) * 128 + c] = (_Float16)(acc[j] + bv);
    if (ch < 3) K1_WRITE(ch + 1);
    __syncthreads();
  }
}

// ---------------------------------------------------------------- K2ru: reset + update fused via wave groups
// grid (128, 4) x 512. Block: 128 rows x 64 cols, BOTH gates (waves 0-3 r, 4-7 u).
// A = [input|prev] fp16, 16-row chunks (2x16 KB LDS), shared by all 8 waves.
__global__ __launch_bounds__(512) void k2ru(
    const float* __restrict__ input, const float* __restrict__ prev,
    const float* __restrict__ br, const float* __restrict__ bu,
    const _Float16* __restrict__ ws,
    _Float16* __restrict__ t_sc, _Float16* __restrict__ u_sc)
{
  __shared__ char smem[2 * 16384];   // 16 rows x [in 512B | prev 512B]
  const int tid = threadIdx.x, w = tid >> 6, l = tid & 63;
  const int lr = l & 15, lg = l >> 4;
  const int rows0 = blockIdx.x * 128;
  const int isU = w >> 2;
  const int c = blockIdx.y * 64 + (w & 3) * 16 + lr;

  const _Float16* W = ws + (isU ? OFF_WUH : OFF_WRH);
  half8 bw[16];
#pragma unroll
  for (int ks = 0; ks < 16; ++ks)
    bw[ks] = *(const half8*)(W + (size_t)c * 512 + ks * 32 + lg * 8);
  const float bv = (isU ? bu : br)[c];

  const int srow = tid >> 5, scol = (tid & 31) * 8;
  const int ssz = (srow & 7) << 4;
  floatx4 sI0, sI1, sP0, sP1;

#define K2RU_LOAD(ch) { \
  const float* si = input + ((size_t)rows0 + (ch) * 16 + srow) * 256 + scol; \
  const float* sp = prev  + ((size_t)rows0 + (ch) * 16 + srow) * 256 + scol; \
  sI0 = *(const floatx4*)si; sI1 = *(const floatx4*)(si + 4); \
  sP0 = *(const floatx4*)sp; sP1 = *(const floatx4*)(sp + 4); }
#define K2RU_WRITE(ch) { char* bufw = smem + ((ch) & 1) * 16384; \
  half8 hi, hp; \
  _Pragma("unroll") for (int j = 0; j < 4; ++j) { \
    hi[j] = (_Float16)sI0[j]; hi[4+j] = (_Float16)sI1[j]; \
    hp[j] = (_Float16)sP0[j]; hp[4+j] = (_Float16)sP1[j]; } \
  int o = srow * 1024 + ((scol * 2) ^ ssz); \
  *(half8*)(bufw + o) = hi; *(half8*)(bufw + o + 512) = hp; }

  K2RU_LOAD(0); K2RU_WRITE(0);
  __syncthreads();
#pragma unroll 1
  for (int ch = 0; ch < 8; ++ch) {
    if (ch < 7) K2RU_LOAD(ch + 1);
    const char* buf = smem + (ch & 1) * 16384;
    floatx4 acc = {0.f, 0.f, 0.f, 0.f};
    const int base = lr * 1024, sz = (lr & 7) << 4;
#pragma unroll
    for (int ks = 0; ks < 16; ++ks) {   // ks>=8 lands in [512,1024) = prev half
      half8 a = *(const half8*)(buf + base + ((ks * 64 + lg * 16) ^ sz));
      acc = MFMA16(a, bw[ks], acc);
    }
#pragma unroll
    for (int j = 0; j < 4; ++j) {
      const int crow = lg * 4 + j;
      const size_t grow = (size_t)rows0 + ch * 16 + crow;
      float g = 1.f / (1.f + __expf(-(acc[j] + bv)));
      if (!isU) {
        float m = (float)*(const _Float16*)(buf + crow * 1024 + 512 + ((c * 2) ^ ((crow & 7) << 4)));
        t_sc[grow * 256 + c] = (_Float16)(g * m);
      } else {
        u_sc[grow * 256 + c] = (_Float16)g;
      }
    }
    if (ch < 7) K2RU_WRITE(ch + 1);
    __syncthreads();
  }
}

// ---------------------------------------------------------------- K2c: candidate + combine -> out0
// grid (256, 2) x 512. Block: 64 rows x 128 cols. A = [input | t], 16-row chunks.
__global__ __launch_bounds__(512) void k2c(
    const float* __restrict__ input, const float* __restrict__ prev,
    const float* __restrict__ bc, const _Float16* __restrict__ ws,
    const _Float16* __restrict__ t_sc, const _Float16* __restrict__ u_sc,
    float* __restrict__ out0)
{
  __shared__ char smem[2 * 16384];   // 16 rows x [in 512B | t 512B]
  const int tid = threadIdx.x, w = tid >> 6, l = tid & 63;
  const int lr = l & 15, lg = l >> 4;
  const int rows0 = blockIdx.x * 64;
  const int c = blockIdx.y * 128 + w * 16 + lr;

  half8 bw[16];
#pragma unroll
  for (int ks = 0; ks < 16; ++ks)
    bw[ks] = *(const half8*)(ws + OFF_WCH + (size_t)c * 512 + ks * 32 + lg * 8);
  const float bv = bc[c];

  const int srow = tid >> 5, scol = (tid & 31) * 8;
  const int ssz = (srow & 7) << 4;
  floatx4 sI0, sI1;
  half8 sT;

#define K2C_LOAD(ch) { \
  const float* si = input + ((size_t)rows0 + (ch) * 16 + srow) * 256 + scol; \
  sI0 = *(const floatx4*)si; sI1 = *(const floatx4*)(si + 4); \
  sT = *(const half8*)(t_sc + ((size_t)rows0 + (ch) * 16 + srow) * 256 + scol); }
#define K2C_WRITE(ch) { char* bufw = smem + ((ch) & 1) * 16384; \
  half8 hi; \
  _Pragma("unroll") for (int j = 0; j < 4; ++j) { hi[j] = (_Float16)sI0[j]; hi[4+j] = (_Float16)sI1[j]; } \
  int o = srow * 1024 + ((scol * 2) ^ ssz); \
  *(half8*)(bufw + o) = hi; *(half8*)(bufw + o + 512) = sT; }

  K2C_LOAD(0); K2C_WRITE(0);
  __syncthreads();
#pragma unroll 1
  for (int ch = 0; ch < 4; ++ch) {
    if (ch < 3) K2C_LOAD(ch + 1);
    const char* buf = smem + (ch & 1) * 16384;
    floatx4 acc = {0.f, 0.f, 0.f, 0.f};
    const int base = lr * 1024, sz = (lr & 7) << 4;
#pragma unroll
    for (int ks = 0; ks < 16; ++ks) {   // ks>=8 = t half
      half8 a = *(const half8*)(buf + base + ((ks * 64 + lg * 16) ^ sz));
      acc = MFMA16(a, bw[ks], acc);
    }
#pragma unroll
    for (int j = 0; j < 4; ++j) {
      const size_t grow = (size_t)rows0 + ch * 16 + lg * 4 + j;
      float e2 = __expf(2.f * (acc[j] + bv));
      float cg = (e2 - 1.f) / (e2 + 1.f);
      float u = (float)u_sc[grow * 256 + c];
      float m = prev[grow * 256 + c];
      out0[grow * 256 + c] = (1.f - u) * m + u * cg;
    }
    if (ch < 3) K2C_WRITE(ch + 1);
    __syncthreads();
  }
}

// ---------------------------------------------------------------- K3: attention, swapped-operand single pass
// grid (8, 128) x 512: x = batch -> XCD (K slice L2-resident). Block = 16 q-rows.
// 8 waves x 256 keys. mfma(K,Q): acc reg j = key kt*16+lg*4+j, lane col lr = q-row.
// Numerators exp(s-14) fp16 in 32 VGPR; epilogue = coalesced float4 stores.
__global__ __launch_bounds__(512) void k3_attn(
    const _Float16* __restrict__ ws, float* __restrict__ out1)
{
  __shared__ float sums[8][16];
  const int b = blockIdx.x;
  const int q0 = blockIdx.y * 16;
  const int tid = threadIdx.x, w = tid >> 6, l = tid & 63;
  const int lr = l & 15, lg = l >> 4;

  const _Float16* Q  = ws + OFF_Q + ((size_t)b * 2048 + q0) * 128;
  const _Float16* Kp = ws + OFF_K + (size_t)b * 2048 * 128 + (size_t)w * 256 * 128;

  half8 qf[4];
#pragma unroll
  for (int ks = 0; ks < 4; ++ks)
    qf[ks] = *(const half8*)(Q + (size_t)lr * 128 + ks * 32 + lg * 8);

  half4 ex[16];
  float se = 0.f;
#pragma unroll 2
  for (int kt = 0; kt < 16; ++kt) {
    const _Float16* kp = Kp + (size_t)(kt * 16 + lr) * 128 + lg * 8;
    half8 kf[4];
#pragma unroll
    for (int ks = 0; ks < 4; ++ks) kf[ks] = *(const half8*)(kp + ks * 32);
    floatx4 acc = {0.f, 0.f, 0.f, 0.f};
#pragma unroll
    for (int ks = 0; ks < 4; ++ks) acc = MFMA16(kf[ks], qf[ks], acc);   // swapped: rows=keys, cols=q
    half4 e;
#pragma unroll
    for (int j = 0; j < 4; ++j) {
      float f = __expf(acc[j] - 14.f);
      se += f;
      e[j] = (_Float16)f;
    }
    ex[kt] = e;
  }
  se += __shfl_xor(se, 16);
  se += __shfl_xor(se, 32);
  if (l < 16) sums[w][l] = se;
  __syncthreads();
  float tot = 0.f;
#pragma unroll
  for (int ww = 0; ww < 8; ++ww) tot += sums[ww][lr];
  const float inv = 1.f / tot;

  float* orow = out1 + ((size_t)b * 2048 + q0 + lr) * 2048 + w * 256;
#pragma unroll
  for (int kt = 0; kt < 16; ++kt) {
    floatx4 v;
#pragma unroll
    for (int j = 0; j < 4; ++j) v[j] = (float)ex[kt][j] * inv;
    *(floatx4*)(orow + kt * 16 + lg * 4) = v;
  }
}

// ----------------------------------------------------------------
extern "C" void kernel_launch(void* const* d_in, const int* in_sizes, int n_in,
                              void* d_out, int out_size, void* d_ws, size_t ws_size,
                              hipStream_t stream)
{
  const float* input = (const float*)d_in[0];
  const float* prev  = (const float*)d_in[1];
  const float* Wq = (const float*)d_in[2];
  const float* bq = (const float*)d_in[3];
  const float* Wk = (const float*)d_in[4];
  const float* bk = (const float*)d_in[5];
  const float* Wu = (const float*)d_in[8];
  const float* bu = (const float*)d_in[9];
  const float* Wr = (const float*)d_in[10];
  const float* br = (const float*)d_in[11];
  const float* Wc = (const float*)d_in[12];
  const float* bc = (const float*)d_in[13];

  float* out0 = (float*)d_out;                        // new_memory [8,2048,256]
  float* out1 = out0 + (size_t)8 * 2048 * 256;        // attention_probs [8,2048,2048]
  _Float16* ws = (_Float16*)d_ws;                     // 9,437,184 bytes used

  // t/u intermediates live in the out1 region (k3 overwrites it afterwards)
  _Float16* t_sc = (_Float16*)out1;                   // 4.19M halves
  _Float16* u_sc = (_Float16*)out1 + 4194304;         // 4.19M halves

  hipLaunchKernelGGL(k0_convert, dim3(1792), dim3(256), 0, stream, Wq, Wk, Wu, Wr, Wc, ws);
  hipLaunchKernelGGL(k1_proj,    dim3(256, 2), dim3(512), 0, stream, input, prev, bq, bk, ws);
  hipLaunchKernelGGL(k2ru,       dim3(128, 4), dim3(512), 0, stream, input, prev, br, bu, ws, t_sc, u_sc);
  hipLaunchKernelGGL(k2c,        dim3(256, 2), dim3(512), 0, stream, input, prev, bc, ws, t_sc, u_sc, out0);
  hipLaunchKernelGGL(k3_attn,    dim3(8, 128), dim3(512), 0, stream, ws, out1);
}

// Round 7
// 151.978 us; speedup vs baseline: 2.1618x; 2.1618x over previous
//
#include <hip/hip_runtime.h>

// DynamicMemoryCell: B=8, N=2048, IN=256, MEM=256, CTX=128
// out0 = new_memory [8,2048,256] f32 ; out1 = attention_probs [8,2048,2048] f32
// Wv/value/context dead in reference -> skipped.
//
// R6: R5 structure; k3 kt-loop FULL-unrolled (R5's `#pragma unroll 2` made
// ex[kt] runtime-indexed -> scratch spill -> 8 GB fetch; rule #20).

typedef _Float16 half8 __attribute__((ext_vector_type(8)));
typedef _Float16 half4 __attribute__((ext_vector_type(4)));
typedef float floatx4 __attribute__((ext_vector_type(4)));

#define MFMA16(a, b, c) __builtin_amdgcn_mfma_f32_16x16x32_f16((a), (b), (c), 0, 0, 0)

// ws layout (units: _Float16)
#define OFF_WQH 0
#define OFF_WQL 32768
#define OFF_WKH 65536
#define OFF_WKL 98304
#define OFF_WUH 131072
#define OFF_WRH 262144
#define OFF_WCH 393216
#define OFF_Q   524288
#define OFF_K   2621440
// total 4718592 halves = 9,437,184 bytes

// ---------------------------------------------------------------- K0: weights fp32 -> fp16 (hi/lo for Wq/Wk)
__global__ __launch_bounds__(256) void k0_convert(
    const float* __restrict__ Wq, const float* __restrict__ Wk,
    const float* __restrict__ Wu, const float* __restrict__ Wr,
    const float* __restrict__ Wc, _Float16* __restrict__ ws)
{
  int i = blockIdx.x * 256 + threadIdx.x;
  if (i < 32768) {
    float w = Wq[i];
    _Float16 h = (_Float16)w;
    ws[OFF_WQH + i] = h;
    ws[OFF_WQL + i] = (_Float16)(w - (float)h);
  } else if (i < 65536) {
    int j = i - 32768;
    float w = Wk[j];
    _Float16 h = (_Float16)w;
    ws[OFF_WKH + j] = h;
    ws[OFF_WKL + j] = (_Float16)(w - (float)h);
  } else {
    int j = i - 65536;
    if (j < 131072)      ws[OFF_WUH + j]            = (_Float16)Wu[j];
    else if (j < 262144) ws[OFF_WRH + (j - 131072)] = (_Float16)Wr[j - 131072];
    else                 ws[OFF_WCH + (j - 262144)] = (_Float16)Wc[j - 262144];
  }
}

// ---------------------------------------------------------------- K1: Q/K projection (split-fp16, 3 products)
// grid (256, 2) x 512. x: 64-row block, y: 0=Q(input,Wq) 1=K(prev,Wk).
// 8 waves x 16 cols (all 128 cols). A hi/lo staged in 16-row chunks (2x16 KB LDS).
__global__ __launch_bounds__(512) void k1_proj(
    const float* __restrict__ input, const float* __restrict__ prev,
    const float* __restrict__ bq, const float* __restrict__ bk,
    _Float16* __restrict__ ws)
{
  __shared__ char smem[2 * 16384];   // 16 rows x [hi 512B | lo 512B]
  const int which = blockIdx.y;
  const float* x = which ? prev : input;
  const _Float16* WH = ws + (which ? OFF_WKH : OFF_WQH);
  const _Float16* WL = ws + (which ? OFF_WKL : OFF_WQL);
  const float* bias = which ? bk : bq;
  _Float16* out = ws + (which ? OFF_K : OFF_Q);

  const int tid = threadIdx.x, w = tid >> 6, l = tid & 63;
  const int lr = l & 15, lg = l >> 4;
  const int rows0 = blockIdx.x * 64;
  const int c = w * 16 + lr;

  half8 bh[8], blo[8];
#pragma unroll
  for (int ks = 0; ks < 8; ++ks) {
    bh[ks]  = *(const half8*)(WH + (size_t)c * 256 + ks * 32 + lg * 8);
    blo[ks] = *(const half8*)(WL + (size_t)c * 256 + ks * 32 + lg * 8);
  }
  const float bv = bias[c];

  const int srow = tid >> 5, scol = (tid & 31) * 8;
  const int ssz = (srow & 7) << 4;
  floatx4 st0, st1;

#define K1_LOAD(ch) { const float* src = x + ((size_t)rows0 + (ch) * 16 + srow) * 256 + scol; \
  st0 = *(const floatx4*)src; st1 = *(const floatx4*)(src + 4); }
#define K1_WRITE(ch) { char* bufw = smem + ((ch) & 1) * 16384; \
  half8 h, lo; \
  _Pragma("unroll") for (int j = 0; j < 4; ++j) { \
    h[j] = (_Float16)st0[j]; lo[j] = (_Float16)(st0[j] - (float)h[j]); \
    h[4+j] = (_Float16)st1[j]; lo[4+j] = (_Float16)(st1[j] - (float)h[4+j]); } \
  int o = srow * 1024 + ((scol * 2) ^ ssz); \
  *(half8*)(bufw + o) = h; *(half8*)(bufw + o + 512) = lo; }

  K1_LOAD(0); K1_WRITE(0);
  __syncthreads();
#pragma unroll 1
  for (int ch = 0; ch < 4; ++ch) {
    if (ch < 3) K1_LOAD(ch + 1);
    const char* buf = smem + (ch & 1) * 16384;
    floatx4 acc = {0.f, 0.f, 0.f, 0.f};
    const int base = lr * 1024, sz = (lr & 7) << 4;
#pragma unroll
    for (int ks = 0; ks < 8; ++ks) {
      int o = base + ((ks * 64 + lg * 16) ^ sz);
      half8 ah = *(const half8*)(buf + o);
      half8 al = *(const half8*)(buf + o + 512);
      acc = MFMA16(ah, bh[ks], acc);
      acc = MFMA16(al, bh[ks], acc);
      acc = MFMA16(ah, blo[ks], acc);
    }
#pragma unroll
    for (int j = 0; j < 4; ++j)
      out[((size_t)rows0 + ch * 16 + lg * 4 + j) * 128 + c] = (_Float16)(acc[j] + bv);
    if (ch < 3) K1_WRITE(ch + 1);
    __syncthreads();
  }
}

// ---------------------------------------------------------------- K2ru: reset + update fused via wave groups
// grid (128, 4) x 512. Block: 128 rows x 64 cols, BOTH gates (waves 0-3 r, 4-7 u).
// A = [input|prev] fp16, 16-row chunks (2x16 KB LDS), shared by all 8 waves.
__global__ __launch_bounds__(512) void k2ru(
    const float* __restrict__ input, const float* __restrict__ prev,
    const float* __restrict__ br, const float* __restrict__ bu,
    const _Float16* __restrict__ ws,
    _Float16* __restrict__ t_sc, _Float16* __restrict__ u_sc)
{
  __shared__ char smem[2 * 16384];   // 16 rows x [in 512B | prev 512B]
  const int tid = threadIdx.x, w = tid >> 6, l = tid & 63;
  const int lr = l & 15, lg = l >> 4;
  const int rows0 = blockIdx.x * 128;
  const int isU = w >> 2;
  const int c = blockIdx.y * 64 + (w & 3) * 16 + lr;

  const _Float16* W = ws + (isU ? OFF_WUH : OFF_WRH);
  half8 bw[16];
#pragma unroll
  for (int ks = 0; ks < 16; ++ks)
    bw[ks] = *(const half8*)(W + (size_t)c * 512 + ks * 32 + lg * 8);
  const float bv = (isU ? bu : br)[c];

  const int srow = tid >> 5, scol = (tid & 31) * 8;
  const int ssz = (srow & 7) << 4;
  floatx4 sI0, sI1, sP0, sP1;

#define K2RU_LOAD(ch) { \
  const float* si = input + ((size_t)rows0 + (ch) * 16 + srow) * 256 + scol; \
  const float* sp = prev  + ((size_t)rows0 + (ch) * 16 + srow) * 256 + scol; \
  sI0 = *(const floatx4*)si; sI1 = *(const floatx4*)(si + 4); \
  sP0 = *(const floatx4*)sp; sP1 = *(const floatx4*)(sp + 4); }
#define K2RU_WRITE(ch) { char* bufw = smem + ((ch) & 1) * 16384; \
  half8 hi, hp; \
  _Pragma("unroll") for (int j = 0; j < 4; ++j) { \
    hi[j] = (_Float16)sI0[j]; hi[4+j] = (_Float16)sI1[j]; \
    hp[j] = (_Float16)sP0[j]; hp[4+j] = (_Float16)sP1[j]; } \
  int o = srow * 1024 + ((scol * 2) ^ ssz); \
  *(half8*)(bufw + o) = hi; *(half8*)(bufw + o + 512) = hp; }

  K2RU_LOAD(0); K2RU_WRITE(0);
  __syncthreads();
#pragma unroll 1
  for (int ch = 0; ch < 8; ++ch) {
    if (ch < 7) K2RU_LOAD(ch + 1);
    const char* buf = smem + (ch & 1) * 16384;
    floatx4 acc = {0.f, 0.f, 0.f, 0.f};
    const int base = lr * 1024, sz = (lr & 7) << 4;
#pragma unroll
    for (int ks = 0; ks < 16; ++ks) {   // ks>=8 lands in [512,1024) = prev half
      half8 a = *(const half8*)(buf + base + ((ks * 64 + lg * 16) ^ sz));
      acc = MFMA16(a, bw[ks], acc);
    }
#pragma unroll
    for (int j = 0; j < 4; ++j) {
      const int crow = lg * 4 + j;
      const size_t grow = (size_t)rows0 + ch * 16 + crow;
      float g = 1.f / (1.f + __expf(-(acc[j] + bv)));
      if (!isU) {
        float m = (float)*(const _Float16*)(buf + crow * 1024 + 512 + ((c * 2) ^ ((crow & 7) << 4)));
        t_sc[grow * 256 + c] = (_Float16)(g * m);
      } else {
        u_sc[grow * 256 + c] = (_Float16)g;
      }
    }
    if (ch < 7) K2RU_WRITE(ch + 1);
    __syncthreads();
  }
}

// ---------------------------------------------------------------- K2c: candidate + combine -> out0
// grid (256, 2) x 512. Block: 64 rows x 128 cols. A = [input | t], 16-row chunks.
__global__ __launch_bounds__(512) void k2c(
    const float* __restrict__ input, const float* __restrict__ prev,
    const float* __restrict__ bc, const _Float16* __restrict__ ws,
    const _Float16* __restrict__ t_sc, const _Float16* __restrict__ u_sc,
    float* __restrict__ out0)
{
  __shared__ char smem[2 * 16384];   // 16 rows x [in 512B | t 512B]
  const int tid = threadIdx.x, w = tid >> 6, l = tid & 63;
  const int lr = l & 15, lg = l >> 4;
  const int rows0 = blockIdx.x * 64;
  const int c = blockIdx.y * 128 + w * 16 + lr;

  half8 bw[16];
#pragma unroll
  for (int ks = 0; ks < 16; ++ks)
    bw[ks] = *(const half8*)(ws + OFF_WCH + (size_t)c * 512 + ks * 32 + lg * 8);
  const float bv = bc[c];

  const int srow = tid >> 5, scol = (tid & 31) * 8;
  const int ssz = (srow & 7) << 4;
  floatx4 sI0, sI1;
  half8 sT;

#define K2C_LOAD(ch) { \
  const float* si = input + ((size_t)rows0 + (ch) * 16 + srow) * 256 + scol; \
  sI0 = *(const floatx4*)si; sI1 = *(const floatx4*)(si + 4); \
  sT = *(const half8*)(t_sc + ((size_t)rows0 + (ch) * 16 + srow) * 256 + scol); }
#define K2C_WRITE(ch) { char* bufw = smem + ((ch) & 1) * 16384; \
  half8 hi; \
  _Pragma("unroll") for (int j = 0; j < 4; ++j) { hi[j] = (_Float16)sI0[j]; hi[4+j] = (_Float16)sI1[j]; } \
  int o = srow * 1024 + ((scol * 2) ^ ssz); \
  *(half8*)(bufw + o) = hi; *(half8*)(bufw + o + 512) = sT; }

  K2C_LOAD(0); K2C_WRITE(0);
  __syncthreads();
#pragma unroll 1
  for (int ch = 0; ch < 4; ++ch) {
    if (ch < 3) K2C_LOAD(ch + 1);
    const char* buf = smem + (ch & 1) * 16384;
    floatx4 acc = {0.f, 0.f, 0.f, 0.f};
    const int base = lr * 1024, sz = (lr & 7) << 4;
#pragma unroll
    for (int ks = 0; ks < 16; ++ks) {   // ks>=8 = t half
      half8 a = *(const half8*)(buf + base + ((ks * 64 + lg * 16) ^ sz));
      acc = MFMA16(a, bw[ks], acc);
    }
#pragma unroll
    for (int j = 0; j < 4; ++j) {
      const size_t grow = (size_t)rows0 + ch * 16 + lg * 4 + j;
      float e2 = __expf(2.f * (acc[j] + bv));
      float cg = (e2 - 1.f) / (e2 + 1.f);
      float u = (float)u_sc[grow * 256 + c];
      float m = prev[grow * 256 + c];
      out0[grow * 256 + c] = (1.f - u) * m + u * cg;
    }
    if (ch < 3) K2C_WRITE(ch + 1);
    __syncthreads();
  }
}

// ---------------------------------------------------------------- K3: attention, swapped-operand single pass
// grid (8, 128) x 512: x = batch -> XCD (K slice L2-resident). Block = 16 q-rows.
// 8 waves x 256 keys. mfma(K,Q): acc reg j = key kt*16+lg*4+j, lane col lr = q-row.
// Numerators exp(s-14) fp16 in 32 VGPR (kt loop FULLY unrolled -> static indexing).
__global__ __launch_bounds__(512) void k3_attn(
    const _Float16* __restrict__ ws, float* __restrict__ out1)
{
  __shared__ float sums[8][16];
  const int b = blockIdx.x;
  const int q0 = blockIdx.y * 16;
  const int tid = threadIdx.x, w = tid >> 6, l = tid & 63;
  const int lr = l & 15, lg = l >> 4;

  const _Float16* Q  = ws + OFF_Q + ((size_t)b * 2048 + q0) * 128;
  const _Float16* Kp = ws + OFF_K + (size_t)b * 2048 * 128 + (size_t)w * 256 * 128;

  half8 qf[4];
#pragma unroll
  for (int ks = 0; ks < 4; ++ks)
    qf[ks] = *(const half8*)(Q + (size_t)lr * 128 + ks * 32 + lg * 8);

  half4 ex[16];
  float se = 0.f;
#pragma unroll
  for (int kt = 0; kt < 16; ++kt) {    // FULL unroll: ex[kt] must be static (rule #20)
    const _Float16* kp = Kp + (size_t)(kt * 16 + lr) * 128 + lg * 8;
    half8 kf[4];
#pragma unroll
    for (int ks = 0; ks < 4; ++ks) kf[ks] = *(const half8*)(kp + ks * 32);
    floatx4 acc = {0.f, 0.f, 0.f, 0.f};
#pragma unroll
    for (int ks = 0; ks < 4; ++ks) acc = MFMA16(kf[ks], qf[ks], acc);   // swapped: rows=keys, cols=q
    half4 e;
#pragma unroll
    for (int j = 0; j < 4; ++j) {
      float f = __expf(acc[j] - 14.f);
      se += f;
      e[j] = (_Float16)f;
    }
    ex[kt] = e;
  }
  se += __shfl_xor(se, 16);
  se += __shfl_xor(se, 32);
  if (l < 16) sums[w][l] = se;
  __syncthreads();
  float tot = 0.f;
#pragma unroll
  for (int ww = 0; ww < 8; ++ww) tot += sums[ww][lr];
  const float inv = 1.f / tot;

  float* orow = out1 + ((size_t)b * 2048 + q0 + lr) * 2048 + w * 256;
#pragma unroll
  for (int kt = 0; kt < 16; ++kt) {
    floatx4 v;
#pragma unroll
    for (int j = 0; j < 4; ++j) v[j] = (float)ex[kt][j] * inv;
    *(floatx4*)(orow + kt * 16 + lg * 4) = v;
  }
}

// ----------------------------------------------------------------
extern "C" void kernel_launch(void* const* d_in, const int* in_sizes, int n_in,
                              void* d_out, int out_size, void* d_ws, size_t ws_size,
                              hipStream_t stream)
{
  const float* input = (const float*)d_in[0];
  const float* prev  = (const float*)d_in[1];
  const float* Wq = (const float*)d_in[2];
  const float* bq = (const float*)d_in[3];
  const float* Wk = (const float*)d_in[4];
  const float* bk = (const float*)d_in[5];
  const float* Wu = (const float*)d_in[8];
  const float* bu = (const float*)d_in[9];
  const float* Wr = (const float*)d_in[10];
  const float* br = (const float*)d_in[11];
  const float* Wc = (const float*)d_in[12];
  const float* bc = (const float*)d_in[13];

  float* out0 = (float*)d_out;                        // new_memory [8,2048,256]
  float* out1 = out0 + (size_t)8 * 2048 * 256;        // attention_probs [8,2048,2048]
  _Float16* ws = (_Float16*)d_ws;                     // 9,437,184 bytes used

  // t/u intermediates live in the out1 region (k3 overwrites it afterwards)
  _Float16* t_sc = (_Float16*)out1;                   // 4.19M halves
  _Float16* u_sc = (_Float16*)out1 + 4194304;         // 4.19M halves

  hipLaunchKernelGGL(k0_convert, dim3(1792), dim3(256), 0, stream, Wq, Wk, Wu, Wr, Wc, ws);
  hipLaunchKernelGGL(k1_proj,    dim3(256, 2), dim3(512), 0, stream, input, prev, bq, bk, ws);
  hipLaunchKernelGGL(k2ru,       dim3(128, 4), dim3(512), 0, stream, input, prev, br, bu, ws, t_sc, u_sc);
  hipLaunchKernelGGL(k2c,        dim3(256, 2), dim3(512), 0, stream, input, prev, bc, ws, t_sc, u_sc, out0);
  hipLaunchKernelGGL(k3_attn,    dim3(8, 128), dim3(512), 0, stream, ws, out1);
}

// Round 8
// 148.587 us; speedup vs baseline: 2.2111x; 1.0228x over previous
//
#include <hip/hip_runtime.h>

// DynamicMemoryCell: B=8, N=2048, IN=256, MEM=256, CTX=128
// out0 = new_memory [8,2048,256] f32 ; out1 = attention_probs [8,2048,2048] f32
// Wv/value/context dead in reference -> skipped.
//
// R7: identical to R6 except k3 gets __launch_bounds__(512,4) (cap ~128 VGPR).
// Theory: full-unroll kt loop ballooned VGPR -> 1 block/CU -> latency-exposed.

typedef _Float16 half8 __attribute__((ext_vector_type(8)));
typedef _Float16 half4 __attribute__((ext_vector_type(4)));
typedef float floatx4 __attribute__((ext_vector_type(4)));

#define MFMA16(a, b, c) __builtin_amdgcn_mfma_f32_16x16x32_f16((a), (b), (c), 0, 0, 0)

// ws layout (units: _Float16)
#define OFF_WQH 0
#define OFF_WQL 32768
#define OFF_WKH 65536
#define OFF_WKL 98304
#define OFF_WUH 131072
#define OFF_WRH 262144
#define OFF_WCH 393216
#define OFF_Q   524288
#define OFF_K   2621440
// total 4718592 halves = 9,437,184 bytes

// ---------------------------------------------------------------- K0: weights fp32 -> fp16 (hi/lo for Wq/Wk)
__global__ __launch_bounds__(256) void k0_convert(
    const float* __restrict__ Wq, const float* __restrict__ Wk,
    const float* __restrict__ Wu, const float* __restrict__ Wr,
    const float* __restrict__ Wc, _Float16* __restrict__ ws)
{
  int i = blockIdx.x * 256 + threadIdx.x;
  if (i < 32768) {
    float w = Wq[i];
    _Float16 h = (_Float16)w;
    ws[OFF_WQH + i] = h;
    ws[OFF_WQL + i] = (_Float16)(w - (float)h);
  } else if (i < 65536) {
    int j = i - 32768;
    float w = Wk[j];
    _Float16 h = (_Float16)w;
    ws[OFF_WKH + j] = h;
    ws[OFF_WKL + j] = (_Float16)(w - (float)h);
  } else {
    int j = i - 65536;
    if (j < 131072)      ws[OFF_WUH + j]            = (_Float16)Wu[j];
    else if (j < 262144) ws[OFF_WRH + (j - 131072)] = (_Float16)Wr[j - 131072];
    else                 ws[OFF_WCH + (j - 262144)] = (_Float16)Wc[j - 262144];
  }
}

// ---------------------------------------------------------------- K1: Q/K projection (split-fp16, 3 products)
// grid (256, 2) x 512. x: 64-row block, y: 0=Q(input,Wq) 1=K(prev,Wk).
// 8 waves x 16 cols (all 128 cols). A hi/lo staged in 16-row chunks (2x16 KB LDS).
__global__ __launch_bounds__(512) void k1_proj(
    const float* __restrict__ input, const float* __restrict__ prev,
    const float* __restrict__ bq, const float* __restrict__ bk,
    _Float16* __restrict__ ws)
{
  __shared__ char smem[2 * 16384];   // 16 rows x [hi 512B | lo 512B]
  const int which = blockIdx.y;
  const float* x = which ? prev : input;
  const _Float16* WH = ws + (which ? OFF_WKH : OFF_WQH);
  const _Float16* WL = ws + (which ? OFF_WKL : OFF_WQL);
  const float* bias = which ? bk : bq;
  _Float16* out = ws + (which ? OFF_K : OFF_Q);

  const int tid = threadIdx.x, w = tid >> 6, l = tid & 63;
  const int lr = l & 15, lg = l >> 4;
  const int rows0 = blockIdx.x * 64;
  const int c = w * 16 + lr;

  half8 bh[8], blo[8];
#pragma unroll
  for (int ks = 0; ks < 8; ++ks) {
    bh[ks]  = *(const half8*)(WH + (size_t)c * 256 + ks * 32 + lg * 8);
    blo[ks] = *(const half8*)(WL + (size_t)c * 256 + ks * 32 + lg * 8);
  }
  const float bv = bias[c];

  const int srow = tid >> 5, scol = (tid & 31) * 8;
  const int ssz = (srow & 7) << 4;
  floatx4 st0, st1;

#define K1_LOAD(ch) { const float* src = x + ((size_t)rows0 + (ch) * 16 + srow) * 256 + scol; \
  st0 = *(const floatx4*)src; st1 = *(const floatx4*)(src + 4); }
#define K1_WRITE(ch) { char* bufw = smem + ((ch) & 1) * 16384; \
  half8 h, lo; \
  _Pragma("unroll") for (int j = 0; j < 4; ++j) { \
    h[j] = (_Float16)st0[j]; lo[j] = (_Float16)(st0[j] - (float)h[j]); \
    h[4+j] = (_Float16)st1[j]; lo[4+j] = (_Float16)(st1[j] - (float)h[4+j]); } \
  int o = srow * 1024 + ((scol * 2) ^ ssz); \
  *(half8*)(bufw + o) = h; *(half8*)(bufw + o + 512) = lo; }

  K1_LOAD(0); K1_WRITE(0);
  __syncthreads();
#pragma unroll 1
  for (int ch = 0; ch < 4; ++ch) {
    if (ch < 3) K1_LOAD(ch + 1);
    const char* buf = smem + (ch & 1) * 16384;
    floatx4 acc = {0.f, 0.f, 0.f, 0.f};
    const int base = lr * 1024, sz = (lr & 7) << 4;
#pragma unroll
    for (int ks = 0; ks < 8; ++ks) {
      int o = base + ((ks * 64 + lg * 16) ^ sz);
      half8 ah = *(const half8*)(buf + o);
      half8 al = *(const half8*)(buf + o + 512);
      acc = MFMA16(ah, bh[ks], acc);
      acc = MFMA16(al, bh[ks], acc);
      acc = MFMA16(ah, blo[ks], acc);
    }
#pragma unroll
    for (int j = 0; j < 4; ++j)
      out[((size_t)rows0 + ch * 16 + lg * 4 + j) * 128 + c] = (_Float16)(acc[j] + bv);
    if (ch < 3) K1_WRITE(ch + 1);
    __syncthreads();
  }
}

// ---------------------------------------------------------------- K2ru: reset + update fused via wave groups
// grid (128, 4) x 512. Block: 128 rows x 64 cols, BOTH gates (waves 0-3 r, 4-7 u).
// A = [input|prev] fp16, 16-row chunks (2x16 KB LDS), shared by all 8 waves.
__global__ __launch_bounds__(512) void k2ru(
    const float* __restrict__ input, const float* __restrict__ prev,
    const float* __restrict__ br, const float* __restrict__ bu,
    const _Float16* __restrict__ ws,
    _Float16* __restrict__ t_sc, _Float16* __restrict__ u_sc)
{
  __shared__ char smem[2 * 16384];   // 16 rows x [in 512B | prev 512B]
  const int tid = threadIdx.x, w = tid >> 6, l = tid & 63;
  const int lr = l & 15, lg = l >> 4;
  const int rows0 = blockIdx.x * 128;
  const int isU = w >> 2;
  const int c = blockIdx.y * 64 + (w & 3) * 16 + lr;

  const _Float16* W = ws + (isU ? OFF_WUH : OFF_WRH);
  half8 bw[16];
#pragma unroll
  for (int ks = 0; ks < 16; ++ks)
    bw[ks] = *(const half8*)(W + (size_t)c * 512 + ks * 32 + lg * 8);
  const float bv = (isU ? bu : br)[c];

  const int srow = tid >> 5, scol = (tid & 31) * 8;
  const int ssz = (srow & 7) << 4;
  floatx4 sI0, sI1, sP0, sP1;

#define K2RU_LOAD(ch) { \
  const float* si = input + ((size_t)rows0 + (ch) * 16 + srow) * 256 + scol; \
  const float* sp = prev  + ((size_t)rows0 + (ch) * 16 + srow) * 256 + scol; \
  sI0 = *(const floatx4*)si; sI1 = *(const floatx4*)(si + 4); \
  sP0 = *(const floatx4*)sp; sP1 = *(const floatx4*)(sp + 4); }
#define K2RU_WRITE(ch) { char* bufw = smem + ((ch) & 1) * 16384; \
  half8 hi, hp; \
  _Pragma("unroll") for (int j = 0; j < 4; ++j) { \
    hi[j] = (_Float16)sI0[j]; hi[4+j] = (_Float16)sI1[j]; \
    hp[j] = (_Float16)sP0[j]; hp[4+j] = (_Float16)sP1[j]; } \
  int o = srow * 1024 + ((scol * 2) ^ ssz); \
  *(half8*)(bufw + o) = hi; *(half8*)(bufw + o + 512) = hp; }

  K2RU_LOAD(0); K2RU_WRITE(0);
  __syncthreads();
#pragma unroll 1
  for (int ch = 0; ch < 8; ++ch) {
    if (ch < 7) K2RU_LOAD(ch + 1);
    const char* buf = smem + (ch & 1) * 16384;
    floatx4 acc = {0.f, 0.f, 0.f, 0.f};
    const int base = lr * 1024, sz = (lr & 7) << 4;
#pragma unroll
    for (int ks = 0; ks < 16; ++ks) {   // ks>=8 lands in [512,1024) = prev half
      half8 a = *(const half8*)(buf + base + ((ks * 64 + lg * 16) ^ sz));
      acc = MFMA16(a, bw[ks], acc);
    }
#pragma unroll
    for (int j = 0; j < 4; ++j) {
      const int crow = lg * 4 + j;
      const size_t grow = (size_t)rows0 + ch * 16 + crow;
      float g = 1.f / (1.f + __expf(-(acc[j] + bv)));
      if (!isU) {
        float m = (float)*(const _Float16*)(buf + crow * 1024 + 512 + ((c * 2) ^ ((crow & 7) << 4)));
        t_sc[grow * 256 + c] = (_Float16)(g * m);
      } else {
        u_sc[grow * 256 + c] = (_Float16)g;
      }
    }
    if (ch < 7) K2RU_WRITE(ch + 1);
    __syncthreads();
  }
}

// ---------------------------------------------------------------- K2c: candidate + combine -> out0
// grid (256, 2) x 512. Block: 64 rows x 128 cols. A = [input | t], 16-row chunks.
__global__ __launch_bounds__(512) void k2c(
    const float* __restrict__ input, const float* __restrict__ prev,
    const float* __restrict__ bc, const _Float16* __restrict__ ws,
    const _Float16* __restrict__ t_sc, const _Float16* __restrict__ u_sc,
    float* __restrict__ out0)
{
  __shared__ char smem[2 * 16384];   // 16 rows x [in 512B | t 512B]
  const int tid = threadIdx.x, w = tid >> 6, l = tid & 63;
  const int lr = l & 15, lg = l >> 4;
  const int rows0 = blockIdx.x * 64;
  const int c = blockIdx.y * 128 + w * 16 + lr;

  half8 bw[16];
#pragma unroll
  for (int ks = 0; ks < 16; ++ks)
    bw[ks] = *(const half8*)(ws + OFF_WCH + (size_t)c * 512 + ks * 32 + lg * 8);
  const float bv = bc[c];

  const int srow = tid >> 5, scol = (tid & 31) * 8;
  const int ssz = (srow & 7) << 4;
  floatx4 sI0, sI1;
  half8 sT;

#define K2C_LOAD(ch) { \
  const float* si = input + ((size_t)rows0 + (ch) * 16 + srow) * 256 + scol; \
  sI0 = *(const floatx4*)si; sI1 = *(const floatx4*)(si + 4); \
  sT = *(const half8*)(t_sc + ((size_t)rows0 + (ch) * 16 + srow) * 256 + scol); }
#define K2C_WRITE(ch) { char* bufw = smem + ((ch) & 1) * 16384; \
  half8 hi; \
  _Pragma("unroll") for (int j = 0; j < 4; ++j) { hi[j] = (_Float16)sI0[j]; hi[4+j] = (_Float16)sI1[j]; } \
  int o = srow * 1024 + ((scol * 2) ^ ssz); \
  *(half8*)(bufw + o) = hi; *(half8*)(bufw + o + 512) = sT; }

  K2C_LOAD(0); K2C_WRITE(0);
  __syncthreads();
#pragma unroll 1
  for (int ch = 0; ch < 4; ++ch) {
    if (ch < 3) K2C_LOAD(ch + 1);
    const char* buf = smem + (ch & 1) * 16384;
    floatx4 acc = {0.f, 0.f, 0.f, 0.f};
    const int base = lr * 1024, sz = (lr & 7) << 4;
#pragma unroll
    for (int ks = 0; ks < 16; ++ks) {   // ks>=8 = t half
      half8 a = *(const half8*)(buf + base + ((ks * 64 + lg * 16) ^ sz));
      acc = MFMA16(a, bw[ks], acc);
    }
#pragma unroll
    for (int j = 0; j < 4; ++j) {
      const size_t grow = (size_t)rows0 + ch * 16 + lg * 4 + j;
      float e2 = __expf(2.f * (acc[j] + bv));
      float cg = (e2 - 1.f) / (e2 + 1.f);
      float u = (float)u_sc[grow * 256 + c];
      float m = prev[grow * 256 + c];
      out0[grow * 256 + c] = (1.f - u) * m + u * cg;
    }
    if (ch < 3) K2C_WRITE(ch + 1);
    __syncthreads();
  }
}

// ---------------------------------------------------------------- K3: attention, swapped-operand single pass
// grid (8, 128) x 512: x = batch -> XCD (K slice L2-resident). Block = 16 q-rows.
// 8 waves x 256 keys. mfma(K,Q): acc reg j = key kt*16+lg*4+j, lane col lr = q-row.
// Numerators exp(s-14) fp16 in 32 VGPR; kt loop FULLY unrolled (static ex index).
// __launch_bounds__(512,4): cap ~128 VGPR so the unroll can't balloon lookahead
// (default 256-VGPR budget -> 1 block/CU -> latency-exposed; R7 theory).
__global__ __launch_bounds__(512, 4) void k3_attn(
    const _Float16* __restrict__ ws, float* __restrict__ out1)
{
  __shared__ float sums[8][16];
  const int b = blockIdx.x;
  const int q0 = blockIdx.y * 16;
  const int tid = threadIdx.x, w = tid >> 6, l = tid & 63;
  const int lr = l & 15, lg = l >> 4;

  const _Float16* Q  = ws + OFF_Q + ((size_t)b * 2048 + q0) * 128;
  const _Float16* Kp = ws + OFF_K + (size_t)b * 2048 * 128 + (size_t)w * 256 * 128;

  half8 qf[4];
#pragma unroll
  for (int ks = 0; ks < 4; ++ks)
    qf[ks] = *(const half8*)(Q + (size_t)lr * 128 + ks * 32 + lg * 8);

  half4 ex[16];
  float se = 0.f;
#pragma unroll
  for (int kt = 0; kt < 16; ++kt) {    // FULL unroll: ex[kt] must be static (rule #20)
    const _Float16* kp = Kp + (size_t)(kt * 16 + lr) * 128 + lg * 8;
    half8 kf[4];
#pragma unroll
    for (int ks = 0; ks < 4; ++ks) kf[ks] = *(const half8*)(kp + ks * 32);
    floatx4 acc = {0.f, 0.f, 0.f, 0.f};
#pragma unroll
    for (int ks = 0; ks < 4; ++ks) acc = MFMA16(kf[ks], qf[ks], acc);   // swapped: rows=keys, cols=q
    half4 e;
#pragma unroll
    for (int j = 0; j < 4; ++j) {
      float f = __expf(acc[j] - 14.f);
      se += f;
      e[j] = (_Float16)f;
    }
    ex[kt] = e;
  }
  se += __shfl_xor(se, 16);
  se += __shfl_xor(se, 32);
  if (l < 16) sums[w][l] = se;
  __syncthreads();
  float tot = 0.f;
#pragma unroll
  for (int ww = 0; ww < 8; ++ww) tot += sums[ww][lr];
  const float inv = 1.f / tot;

  float* orow = out1 + ((size_t)b * 2048 + q0 + lr) * 2048 + w * 256;
#pragma unroll
  for (int kt = 0; kt < 16; ++kt) {
    floatx4 v;
#pragma unroll
    for (int j = 0; j < 4; ++j) v[j] = (float)ex[kt][j] * inv;
    *(floatx4*)(orow + kt * 16 + lg * 4) = v;
  }
}

// ----------------------------------------------------------------
extern "C" void kernel_launch(void* const* d_in, const int* in_sizes, int n_in,
                              void* d_out, int out_size, void* d_ws, size_t ws_size,
                              hipStream_t stream)
{
  const float* input = (const float*)d_in[0];
  const float* prev  = (const float*)d_in[1];
  const float* Wq = (const float*)d_in[2];
  const float* bq = (const float*)d_in[3];
  const float* Wk = (const float*)d_in[4];
  const float* bk = (const float*)d_in[5];
  const float* Wu = (const float*)d_in[8];
  const float* bu = (const float*)d_in[9];
  const float* Wr = (const float*)d_in[10];
  const float* br = (const float*)d_in[11];
  const float* Wc = (const float*)d_in[12];
  const float* bc = (const float*)d_in[13];

  float* out0 = (float*)d_out;                        // new_memory [8,2048,256]
  float* out1 = out0 + (size_t)8 * 2048 * 256;        // attention_probs [8,2048,2048]
  _Float16* ws = (_Float16*)d_ws;                     // 9,437,184 bytes used

  // t/u intermediates live in the out1 region (k3 overwrites it afterwards)
  _Float16* t_sc = (_Float16*)out1;                   // 4.19M halves
  _Float16* u_sc = (_Float16*)out1 + 4194304;         // 4.19M halves

  hipLaunchKernelGGL(k0_convert, dim3(1792), dim3(256), 0, stream, Wq, Wk, Wu, Wr, Wc, ws);
  hipLaunchKernelGGL(k1_proj,    dim3(256, 2), dim3(512), 0, stream, input, prev, bq, bk, ws);
  hipLaunchKernelGGL(k2ru,       dim3(128, 4), dim3(512), 0, stream, input, prev, br, bu, ws, t_sc, u_sc);
  hipLaunchKernelGGL(k2c,        dim3(256, 2), dim3(512), 0, stream, input, prev, bc, ws, t_sc, u_sc, out0);
  hipLaunchKernelGGL(k3_attn,    dim3(8, 128), dim3(512), 0, stream, ws, out1);
}

// Round 9
// 147.517 us; speedup vs baseline: 2.2272x; 1.0072x over previous
//
#include <hip/hip_runtime.h>

// DynamicMemoryCell: B=8, N=2048, IN=256, MEM=256, CTX=128
// out0 = new_memory [8,2048,256] f32 ; out1 = attention_probs [8,2048,2048] f32
// Wv/value/context dead in reference -> skipped.
//
// R8: k3 redesigned -- numerators exp(s-14) go to a 64 KB swizzled LDS buffer
// (not registers): compute phase has no register retention (no forced unroll,
// deep pipelining, tiny VGPR); store phase reads LDS linearly and writes
// 512 B contiguous per wave-instruction. k0/k1/k2ru/k2c identical to R7.

typedef _Float16 half8 __attribute__((ext_vector_type(8)));
typedef _Float16 half4 __attribute__((ext_vector_type(4)));
typedef float floatx4 __attribute__((ext_vector_type(4)));

#define MFMA16(a, b, c) __builtin_amdgcn_mfma_f32_16x16x32_f16((a), (b), (c), 0, 0, 0)

// ws layout (units: _Float16)
#define OFF_WQH 0
#define OFF_WQL 32768
#define OFF_WKH 65536
#define OFF_WKL 98304
#define OFF_WUH 131072
#define OFF_WRH 262144
#define OFF_WCH 393216
#define OFF_Q   524288
#define OFF_K   2621440
// total 4718592 halves = 9,437,184 bytes

// ---------------------------------------------------------------- K0: weights fp32 -> fp16 (hi/lo for Wq/Wk)
__global__ __launch_bounds__(256) void k0_convert(
    const float* __restrict__ Wq, const float* __restrict__ Wk,
    const float* __restrict__ Wu, const float* __restrict__ Wr,
    const float* __restrict__ Wc, _Float16* __restrict__ ws)
{
  int i = blockIdx.x * 256 + threadIdx.x;
  if (i < 32768) {
    float w = Wq[i];
    _Float16 h = (_Float16)w;
    ws[OFF_WQH + i] = h;
    ws[OFF_WQL + i] = (_Float16)(w - (float)h);
  } else if (i < 65536) {
    int j = i - 32768;
    float w = Wk[j];
    _Float16 h = (_Float16)w;
    ws[OFF_WKH + j] = h;
    ws[OFF_WKL + j] = (_Float16)(w - (float)h);
  } else {
    int j = i - 65536;
    if (j < 131072)      ws[OFF_WUH + j]            = (_Float16)Wu[j];
    else if (j < 262144) ws[OFF_WRH + (j - 131072)] = (_Float16)Wr[j - 131072];
    else                 ws[OFF_WCH + (j - 262144)] = (_Float16)Wc[j - 262144];
  }
}

// ---------------------------------------------------------------- K1: Q/K projection (split-fp16, 3 products)
__global__ __launch_bounds__(512) void k1_proj(
    const float* __restrict__ input, const float* __restrict__ prev,
    const float* __restrict__ bq, const float* __restrict__ bk,
    _Float16* __restrict__ ws)
{
  __shared__ char smem[2 * 16384];   // 16 rows x [hi 512B | lo 512B]
  const int which = blockIdx.y;
  const float* x = which ? prev : input;
  const _Float16* WH = ws + (which ? OFF_WKH : OFF_WQH);
  const _Float16* WL = ws + (which ? OFF_WKL : OFF_WQL);
  const float* bias = which ? bk : bq;
  _Float16* out = ws + (which ? OFF_K : OFF_Q);

  const int tid = threadIdx.x, w = tid >> 6, l = tid & 63;
  const int lr = l & 15, lg = l >> 4;
  const int rows0 = blockIdx.x * 64;
  const int c = w * 16 + lr;

  half8 bh[8], blo[8];
#pragma unroll
  for (int ks = 0; ks < 8; ++ks) {
    bh[ks]  = *(const half8*)(WH + (size_t)c * 256 + ks * 32 + lg * 8);
    blo[ks] = *(const half8*)(WL + (size_t)c * 256 + ks * 32 + lg * 8);
  }
  const float bv = bias[c];

  const int srow = tid >> 5, scol = (tid & 31) * 8;
  const int ssz = (srow & 7) << 4;
  floatx4 st0, st1;

#define K1_LOAD(ch) { const float* src = x + ((size_t)rows0 + (ch) * 16 + srow) * 256 + scol; \
  st0 = *(const floatx4*)src; st1 = *(const floatx4*)(src + 4); }
#define K1_WRITE(ch) { char* bufw = smem + ((ch) & 1) * 16384; \
  half8 h, lo; \
  _Pragma("unroll") for (int j = 0; j < 4; ++j) { \
    h[j] = (_Float16)st0[j]; lo[j] = (_Float16)(st0[j] - (float)h[j]); \
    h[4+j] = (_Float16)st1[j]; lo[4+j] = (_Float16)(st1[j] - (float)h[4+j]); } \
  int o = srow * 1024 + ((scol * 2) ^ ssz); \
  *(half8*)(bufw + o) = h; *(half8*)(bufw + o + 512) = lo; }

  K1_LOAD(0); K1_WRITE(0);
  __syncthreads();
#pragma unroll 1
  for (int ch = 0; ch < 4; ++ch) {
    if (ch < 3) K1_LOAD(ch + 1);
    const char* buf = smem + (ch & 1) * 16384;
    floatx4 acc = {0.f, 0.f, 0.f, 0.f};
    const int base = lr * 1024, sz = (lr & 7) << 4;
#pragma unroll
    for (int ks = 0; ks < 8; ++ks) {
      int o = base + ((ks * 64 + lg * 16) ^ sz);
      half8 ah = *(const half8*)(buf + o);
      half8 al = *(const half8*)(buf + o + 512);
      acc = MFMA16(ah, bh[ks], acc);
      acc = MFMA16(al, bh[ks], acc);
      acc = MFMA16(ah, blo[ks], acc);
    }
#pragma unroll
    for (int j = 0; j < 4; ++j)
      out[((size_t)rows0 + ch * 16 + lg * 4 + j) * 128 + c] = (_Float16)(acc[j] + bv);
    if (ch < 3) K1_WRITE(ch + 1);
    __syncthreads();
  }
}

// ---------------------------------------------------------------- K2ru: reset + update fused via wave groups
__global__ __launch_bounds__(512) void k2ru(
    const float* __restrict__ input, const float* __restrict__ prev,
    const float* __restrict__ br, const float* __restrict__ bu,
    const _Float16* __restrict__ ws,
    _Float16* __restrict__ t_sc, _Float16* __restrict__ u_sc)
{
  __shared__ char smem[2 * 16384];   // 16 rows x [in 512B | prev 512B]
  const int tid = threadIdx.x, w = tid >> 6, l = tid & 63;
  const int lr = l & 15, lg = l >> 4;
  const int rows0 = blockIdx.x * 128;
  const int isU = w >> 2;
  const int c = blockIdx.y * 64 + (w & 3) * 16 + lr;

  const _Float16* W = ws + (isU ? OFF_WUH : OFF_WRH);
  half8 bw[16];
#pragma unroll
  for (int ks = 0; ks < 16; ++ks)
    bw[ks] = *(const half8*)(W + (size_t)c * 512 + ks * 32 + lg * 8);
  const float bv = (isU ? bu : br)[c];

  const int srow = tid >> 5, scol = (tid & 31) * 8;
  const int ssz = (srow & 7) << 4;
  floatx4 sI0, sI1, sP0, sP1;

#define K2RU_LOAD(ch) { \
  const float* si = input + ((size_t)rows0 + (ch) * 16 + srow) * 256 + scol; \
  const float* sp = prev  + ((size_t)rows0 + (ch) * 16 + srow) * 256 + scol; \
  sI0 = *(const floatx4*)si; sI1 = *(const floatx4*)(si + 4); \
  sP0 = *(const floatx4*)sp; sP1 = *(const floatx4*)(sp + 4); }
#define K2RU_WRITE(ch) { char* bufw = smem + ((ch) & 1) * 16384; \
  half8 hi, hp; \
  _Pragma("unroll") for (int j = 0; j < 4; ++j) { \
    hi[j] = (_Float16)sI0[j]; hi[4+j] = (_Float16)sI1[j]; \
    hp[j] = (_Float16)sP0[j]; hp[4+j] = (_Float16)sP1[j]; } \
  int o = srow * 1024 + ((scol * 2) ^ ssz); \
  *(half8*)(bufw + o) = hi; *(half8*)(bufw + o + 512) = hp; }

  K2RU_LOAD(0); K2RU_WRITE(0);
  __syncthreads();
#pragma unroll 1
  for (int ch = 0; ch < 8; ++ch) {
    if (ch < 7) K2RU_LOAD(ch + 1);
    const char* buf = smem + (ch & 1) * 16384;
    floatx4 acc = {0.f, 0.f, 0.f, 0.f};
    const int base = lr * 1024, sz = (lr & 7) << 4;
#pragma unroll
    for (int ks = 0; ks < 16; ++ks) {   // ks>=8 lands in [512,1024) = prev half
      half8 a = *(const half8*)(buf + base + ((ks * 64 + lg * 16) ^ sz));
      acc = MFMA16(a, bw[ks], acc);
    }
#pragma unroll
    for (int j = 0; j < 4; ++j) {
      const int crow = lg * 4 + j;
      const size_t grow = (size_t)rows0 + ch * 16 + crow;
      float g = 1.f / (1.f + __expf(-(acc[j] + bv)));
      if (!isU) {
        float m = (float)*(const _Float16*)(buf + crow * 1024 + 512 + ((c * 2) ^ ((crow & 7) << 4)));
        t_sc[grow * 256 + c] = (_Float16)(g * m);
      } else {
        u_sc[grow * 256 + c] = (_Float16)g;
      }
    }
    if (ch < 7) K2RU_WRITE(ch + 1);
    __syncthreads();
  }
}

// ---------------------------------------------------------------- K2c: candidate + combine -> out0
__global__ __launch_bounds__(512) void k2c(
    const float* __restrict__ input, const float* __restrict__ prev,
    const float* __restrict__ bc, const _Float16* __restrict__ ws,
    const _Float16* __restrict__ t_sc, const _Float16* __restrict__ u_sc,
    float* __restrict__ out0)
{
  __shared__ char smem[2 * 16384];   // 16 rows x [in 512B | t 512B]
  const int tid = threadIdx.x, w = tid >> 6, l = tid & 63;
  const int lr = l & 15, lg = l >> 4;
  const int rows0 = blockIdx.x * 64;
  const int c = blockIdx.y * 128 + w * 16 + lr;

  half8 bw[16];
#pragma unroll
  for (int ks = 0; ks < 16; ++ks)
    bw[ks] = *(const half8*)(ws + OFF_WCH + (size_t)c * 512 + ks * 32 + lg * 8);
  const float bv = bc[c];

  const int srow = tid >> 5, scol = (tid & 31) * 8;
  const int ssz = (srow & 7) << 4;
  floatx4 sI0, sI1;
  half8 sT;

#define K2C_LOAD(ch) { \
  const float* si = input + ((size_t)rows0 + (ch) * 16 + srow) * 256 + scol; \
  sI0 = *(const floatx4*)si; sI1 = *(const floatx4*)(si + 4); \
  sT = *(const half8*)(t_sc + ((size_t)rows0 + (ch) * 16 + srow) * 256 + scol); }
#define K2C_WRITE(ch) { char* bufw = smem + ((ch) & 1) * 16384; \
  half8 hi; \
  _Pragma("unroll") for (int j = 0; j < 4; ++j) { hi[j] = (_Float16)sI0[j]; hi[4+j] = (_Float16)sI1[j]; } \
  int o = srow * 1024 + ((scol * 2) ^ ssz); \
  *(half8*)(bufw + o) = hi; *(half8*)(bufw + o + 512) = sT; }

  K2C_LOAD(0); K2C_WRITE(0);
  __syncthreads();
#pragma unroll 1
  for (int ch = 0; ch < 4; ++ch) {
    if (ch < 3) K2C_LOAD(ch + 1);
    const char* buf = smem + (ch & 1) * 16384;
    floatx4 acc = {0.f, 0.f, 0.f, 0.f};
    const int base = lr * 1024, sz = (lr & 7) << 4;
#pragma unroll
    for (int ks = 0; ks < 16; ++ks) {   // ks>=8 = t half
      half8 a = *(const half8*)(buf + base + ((ks * 64 + lg * 16) ^ sz));
      acc = MFMA16(a, bw[ks], acc);
    }
#pragma unroll
    for (int j = 0; j < 4; ++j) {
      const size_t grow = (size_t)rows0 + ch * 16 + lg * 4 + j;
      float e2 = __expf(2.f * (acc[j] + bv));
      float cg = (e2 - 1.f) / (e2 + 1.f);
      float u = (float)u_sc[grow * 256 + c];
      float m = prev[grow * 256 + c];
      out0[grow * 256 + c] = (1.f - u) * m + u * cg;
    }
    if (ch < 3) K2C_WRITE(ch + 1);
    __syncthreads();
  }
}

// ---------------------------------------------------------------- K3: attention via LDS numerator buffer
// grid (8, 128) x 512: x = batch -> XCD (K slice L2-resident). Block = 16 q-rows x 2048 keys.
// Phase A: 8 waves x 256 keys; mfma(K,Q) swapped; exp(s-14) fp16 -> swizzled LDS [16][2048].
// Phase B: coalesced normalize+store; each wave writes 2x512 B contiguous per instruction.
__global__ __launch_bounds__(512, 4) void k3_attn(
    const _Float16* __restrict__ ws, float* __restrict__ out1)
{
  __shared__ char snum[16 * 4096];   // fp16 numerators [qrow][key], XOR-swizzled
  __shared__ float sums[8][16];
  const int b = blockIdx.x;
  const int q0 = blockIdx.y * 16;
  const int tid = threadIdx.x, w = tid >> 6, l = tid & 63;
  const int lr = l & 15, lg = l >> 4;

  const _Float16* Q  = ws + OFF_Q + ((size_t)b * 2048 + q0) * 128;
  const _Float16* Kp = ws + OFF_K + (size_t)b * 2048 * 128 + (size_t)w * 256 * 128;

  half8 qf[4];
#pragma unroll
  for (int ks = 0; ks < 4; ++ks)
    qf[ks] = *(const half8*)(Q + (size_t)lr * 128 + ks * 32 + lg * 8);

  // ---- Phase A: scores -> exp -> LDS (no register retention)
  const int wbase2 = (w * 256) * 2;        // byte offset of this wave's key slice in a row
  const int asz = (lr & 7) << 4;
  float se = 0.f;
#pragma unroll 2
  for (int kt = 0; kt < 16; ++kt) {
    const _Float16* kp = Kp + (size_t)(kt * 16 + lr) * 128 + lg * 8;
    half8 kf[4];
#pragma unroll
    for (int ks = 0; ks < 4; ++ks) kf[ks] = *(const half8*)(kp + ks * 32);
    floatx4 acc = {0.f, 0.f, 0.f, 0.f};
#pragma unroll
    for (int ks = 0; ks < 4; ++ks) acc = MFMA16(kf[ks], qf[ks], acc);   // swapped: rows=keys, cols=q
    half4 e;
#pragma unroll
    for (int j = 0; j < 4; ++j) {
      float f = __expf(acc[j] - 14.f);
      se += f;
      e[j] = (_Float16)f;
    }
    *(half4*)(snum + lr * 4096 + ((wbase2 + kt * 32 + lg * 8) ^ asz)) = e;
  }
  se += __shfl_xor(se, 16);
  se += __shfl_xor(se, 32);
  if (l < 16) sums[w][l] = se;
  __syncthreads();

  // ---- Phase B: normalize + coalesced store
  const int r = w * 2 + (l >> 5);          // q-row 0..15
  const int cpos = l & 31;
  float tot = 0.f;
#pragma unroll
  for (int ww = 0; ww < 8; ++ww) tot += sums[ww][r];
  const float inv = 1.f / tot;

  float* orow = out1 + ((size_t)b * 2048 + q0 + r) * 2048;
  const int rbase = r * 4096, rsz = (r & 7) << 4;
#pragma unroll
  for (int j = 0; j < 16; ++j) {
    half4 h = *(const half4*)(snum + rbase + ((j * 256 + cpos * 8) ^ rsz));
    floatx4 v;
#pragma unroll
    for (int q = 0; q < 4; ++q) v[q] = (float)h[q] * inv;
    *(floatx4*)(orow + j * 128 + cpos * 4) = v;
  }
}

// ----------------------------------------------------------------
extern "C" void kernel_launch(void* const* d_in, const int* in_sizes, int n_in,
                              void* d_out, int out_size, void* d_ws, size_t ws_size,
                              hipStream_t stream)
{
  const float* input = (const float*)d_in[0];
  const float* prev  = (const float*)d_in[1];
  const float* Wq = (const float*)d_in[2];
  const float* bq = (const float*)d_in[3];
  const float* Wk = (const float*)d_in[4];
  const float* bk = (const float*)d_in[5];
  const float* Wu = (const float*)d_in[8];
  const float* bu = (const float*)d_in[9];
  const float* Wr = (const float*)d_in[10];
  const float* br = (const float*)d_in[11];
  const float* Wc = (const float*)d_in[12];
  const float* bc = (const float*)d_in[13];

  float* out0 = (float*)d_out;                        // new_memory [8,2048,256]
  float* out1 = out0 + (size_t)8 * 2048 * 256;        // attention_probs [8,2048,2048]
  _Float16* ws = (_Float16*)d_ws;                     // 9,437,184 bytes used

  // t/u intermediates live in the out1 region (k3 overwrites it afterwards)
  _Float16* t_sc = (_Float16*)out1;                   // 4.19M halves
  _Float16* u_sc = (_Float16*)out1 + 4194304;         // 4.19M halves

  hipLaunchKernelGGL(k0_convert, dim3(1792), dim3(256), 0, stream, Wq, Wk, Wu, Wr, Wc, ws);
  hipLaunchKernelGGL(k1_proj,    dim3(256, 2), dim3(512), 0, stream, input, prev, bq, bk, ws);
  hipLaunchKernelGGL(k2ru,       dim3(128, 4), dim3(512), 0, stream, input, prev, br, bu, ws, t_sc, u_sc);
  hipLaunchKernelGGL(k2c,        dim3(256, 2), dim3(512), 0, stream, input, prev, bc, ws, t_sc, u_sc, out0);
  hipLaunchKernelGGL(k3_attn,    dim3(8, 128), dim3(512), 0, stream, ws, out1);
}

// Round 10
// 129.016 us; speedup vs baseline: 2.5466x; 1.1434x over previous
//
#include <hip/hip_runtime.h>

// DynamicMemoryCell: B=8, N=2048, IN=256, MEM=256, CTX=128
// out0 = new_memory [8,2048,256] f32 ; out1 = attention_probs [8,2048,2048] f32
// Wv/value/context dead in reference -> skipped.
//
// R9: k3 split into k3a (row-sums, no stores) + k3b (recompute+normalize+store),
// q-tile 64 rows (4x fewer K re-reads: 512->256 MB), grid (8,32,2) = 2 blocks/CU.
// Partial sums live in the dead WQ/WK hi-lo ws region (k1 finished with it).
// k0/k1/k2ru/k2c byte-identical to R8.

typedef _Float16 half8 __attribute__((ext_vector_type(8)));
typedef _Float16 half4 __attribute__((ext_vector_type(4)));
typedef float floatx4 __attribute__((ext_vector_type(4)));

#define MFMA16(a, b, c) __builtin_amdgcn_mfma_f32_16x16x32_f16((a), (b), (c), 0, 0, 0)

// ws layout (units: _Float16)
#define OFF_WQH 0
#define OFF_WQL 32768
#define OFF_WKH 65536
#define OFF_WKL 98304
#define OFF_WUH 131072
#define OFF_WRH 262144
#define OFF_WCH 393216
#define OFF_Q   524288
#define OFF_K   2621440
// total 4718592 halves = 9,437,184 bytes
// After k1, [OFF_WQH .. OFF_WUH) is dead -> reused as f32 partial sums (128 KB).

// ---------------------------------------------------------------- K0: weights fp32 -> fp16 (hi/lo for Wq/Wk)
__global__ __launch_bounds__(256) void k0_convert(
    const float* __restrict__ Wq, const float* __restrict__ Wk,
    const float* __restrict__ Wu, const float* __restrict__ Wr,
    const float* __restrict__ Wc, _Float16* __restrict__ ws)
{
  int i = blockIdx.x * 256 + threadIdx.x;
  if (i < 32768) {
    float w = Wq[i];
    _Float16 h = (_Float16)w;
    ws[OFF_WQH + i] = h;
    ws[OFF_WQL + i] = (_Float16)(w - (float)h);
  } else if (i < 65536) {
    int j = i - 32768;
    float w = Wk[j];
    _Float16 h = (_Float16)w;
    ws[OFF_WKH + j] = h;
    ws[OFF_WKL + j] = (_Float16)(w - (float)h);
  } else {
    int j = i - 65536;
    if (j < 131072)      ws[OFF_WUH + j]            = (_Float16)Wu[j];
    else if (j < 262144) ws[OFF_WRH + (j - 131072)] = (_Float16)Wr[j - 131072];
    else                 ws[OFF_WCH + (j - 262144)] = (_Float16)Wc[j - 262144];
  }
}

// ---------------------------------------------------------------- K1: Q/K projection (split-fp16, 3 products)
__global__ __launch_bounds__(512) void k1_proj(
    const float* __restrict__ input, const float* __restrict__ prev,
    const float* __restrict__ bq, const float* __restrict__ bk,
    _Float16* __restrict__ ws)
{
  __shared__ char smem[2 * 16384];   // 16 rows x [hi 512B | lo 512B]
  const int which = blockIdx.y;
  const float* x = which ? prev : input;
  const _Float16* WH = ws + (which ? OFF_WKH : OFF_WQH);
  const _Float16* WL = ws + (which ? OFF_WKL : OFF_WQL);
  const float* bias = which ? bk : bq;
  _Float16* out = ws + (which ? OFF_K : OFF_Q);

  const int tid = threadIdx.x, w = tid >> 6, l = tid & 63;
  const int lr = l & 15, lg = l >> 4;
  const int rows0 = blockIdx.x * 64;
  const int c = w * 16 + lr;

  half8 bh[8], blo[8];
#pragma unroll
  for (int ks = 0; ks < 8; ++ks) {
    bh[ks]  = *(const half8*)(WH + (size_t)c * 256 + ks * 32 + lg * 8);
    blo[ks] = *(const half8*)(WL + (size_t)c * 256 + ks * 32 + lg * 8);
  }
  const float bv = bias[c];

  const int srow = tid >> 5, scol = (tid & 31) * 8;
  const int ssz = (srow & 7) << 4;
  floatx4 st0, st1;

#define K1_LOAD(ch) { const float* src = x + ((size_t)rows0 + (ch) * 16 + srow) * 256 + scol; \
  st0 = *(const floatx4*)src; st1 = *(const floatx4*)(src + 4); }
#define K1_WRITE(ch) { char* bufw = smem + ((ch) & 1) * 16384; \
  half8 h, lo; \
  _Pragma("unroll") for (int j = 0; j < 4; ++j) { \
    h[j] = (_Float16)st0[j]; lo[j] = (_Float16)(st0[j] - (float)h[j]); \
    h[4+j] = (_Float16)st1[j]; lo[4+j] = (_Float16)(st1[j] - (float)h[4+j]); } \
  int o = srow * 1024 + ((scol * 2) ^ ssz); \
  *(half8*)(bufw + o) = h; *(half8*)(bufw + o + 512) = lo; }

  K1_LOAD(0); K1_WRITE(0);
  __syncthreads();
#pragma unroll 1
  for (int ch = 0; ch < 4; ++ch) {
    if (ch < 3) K1_LOAD(ch + 1);
    const char* buf = smem + (ch & 1) * 16384;
    floatx4 acc = {0.f, 0.f, 0.f, 0.f};
    const int base = lr * 1024, sz = (lr & 7) << 4;
#pragma unroll
    for (int ks = 0; ks < 8; ++ks) {
      int o = base + ((ks * 64 + lg * 16) ^ sz);
      half8 ah = *(const half8*)(buf + o);
      half8 al = *(const half8*)(buf + o + 512);
      acc = MFMA16(ah, bh[ks], acc);
      acc = MFMA16(al, bh[ks], acc);
      acc = MFMA16(ah, blo[ks], acc);
    }
#pragma unroll
    for (int j = 0; j < 4; ++j)
      out[((size_t)rows0 + ch * 16 + lg * 4 + j) * 128 + c] = (_Float16)(acc[j] + bv);
    if (ch < 3) K1_WRITE(ch + 1);
    __syncthreads();
  }
}

// ---------------------------------------------------------------- K2ru: reset + update fused via wave groups
__global__ __launch_bounds__(512) void k2ru(
    const float* __restrict__ input, const float* __restrict__ prev,
    const float* __restrict__ br, const float* __restrict__ bu,
    const _Float16* __restrict__ ws,
    _Float16* __restrict__ t_sc, _Float16* __restrict__ u_sc)
{
  __shared__ char smem[2 * 16384];   // 16 rows x [in 512B | prev 512B]
  const int tid = threadIdx.x, w = tid >> 6, l = tid & 63;
  const int lr = l & 15, lg = l >> 4;
  const int rows0 = blockIdx.x * 128;
  const int isU = w >> 2;
  const int c = blockIdx.y * 64 + (w & 3) * 16 + lr;

  const _Float16* W = ws + (isU ? OFF_WUH : OFF_WRH);
  half8 bw[16];
#pragma unroll
  for (int ks = 0; ks < 16; ++ks)
    bw[ks] = *(const half8*)(W + (size_t)c * 512 + ks * 32 + lg * 8);
  const float bv = (isU ? bu : br)[c];

  const int srow = tid >> 5, scol = (tid & 31) * 8;
  const int ssz = (srow & 7) << 4;
  floatx4 sI0, sI1, sP0, sP1;

#define K2RU_LOAD(ch) { \
  const float* si = input + ((size_t)rows0 + (ch) * 16 + srow) * 256 + scol; \
  const float* sp = prev  + ((size_t)rows0 + (ch) * 16 + srow) * 256 + scol; \
  sI0 = *(const floatx4*)si; sI1 = *(const floatx4*)(si + 4); \
  sP0 = *(const floatx4*)sp; sP1 = *(const floatx4*)(sp + 4); }
#define K2RU_WRITE(ch) { char* bufw = smem + ((ch) & 1) * 16384; \
  half8 hi, hp; \
  _Pragma("unroll") for (int j = 0; j < 4; ++j) { \
    hi[j] = (_Float16)sI0[j]; hi[4+j] = (_Float16)sI1[j]; \
    hp[j] = (_Float16)sP0[j]; hp[4+j] = (_Float16)sP1[j]; } \
  int o = srow * 1024 + ((scol * 2) ^ ssz); \
  *(half8*)(bufw + o) = hi; *(half8*)(bufw + o + 512) = hp; }

  K2RU_LOAD(0); K2RU_WRITE(0);
  __syncthreads();
#pragma unroll 1
  for (int ch = 0; ch < 8; ++ch) {
    if (ch < 7) K2RU_LOAD(ch + 1);
    const char* buf = smem + (ch & 1) * 16384;
    floatx4 acc = {0.f, 0.f, 0.f, 0.f};
    const int base = lr * 1024, sz = (lr & 7) << 4;
#pragma unroll
    for (int ks = 0; ks < 16; ++ks) {   // ks>=8 lands in [512,1024) = prev half
      half8 a = *(const half8*)(buf + base + ((ks * 64 + lg * 16) ^ sz));
      acc = MFMA16(a, bw[ks], acc);
    }
#pragma unroll
    for (int j = 0; j < 4; ++j) {
      const int crow = lg * 4 + j;
      const size_t grow = (size_t)rows0 + ch * 16 + crow;
      float g = 1.f / (1.f + __expf(-(acc[j] + bv)));
      if (!isU) {
        float m = (float)*(const _Float16*)(buf + crow * 1024 + 512 + ((c * 2) ^ ((crow & 7) << 4)));
        t_sc[grow * 256 + c] = (_Float16)(g * m);
      } else {
        u_sc[grow * 256 + c] = (_Float16)g;
      }
    }
    if (ch < 7) K2RU_WRITE(ch + 1);
    __syncthreads();
  }
}

// ---------------------------------------------------------------- K2c: candidate + combine -> out0
__global__ __launch_bounds__(512) void k2c(
    const float* __restrict__ input, const float* __restrict__ prev,
    const float* __restrict__ bc, const _Float16* __restrict__ ws,
    const _Float16* __restrict__ t_sc, const _Float16* __restrict__ u_sc,
    float* __restrict__ out0)
{
  __shared__ char smem[2 * 16384];   // 16 rows x [in 512B | t 512B]
  const int tid = threadIdx.x, w = tid >> 6, l = tid & 63;
  const int lr = l & 15, lg = l >> 4;
  const int rows0 = blockIdx.x * 64;
  const int c = blockIdx.y * 128 + w * 16 + lr;

  half8 bw[16];
#pragma unroll
  for (int ks = 0; ks < 16; ++ks)
    bw[ks] = *(const half8*)(ws + OFF_WCH + (size_t)c * 512 + ks * 32 + lg * 8);
  const float bv = bc[c];

  const int srow = tid >> 5, scol = (tid & 31) * 8;
  const int ssz = (srow & 7) << 4;
  floatx4 sI0, sI1;
  half8 sT;

#define K2C_LOAD(ch) { \
  const float* si = input + ((size_t)rows0 + (ch) * 16 + srow) * 256 + scol; \
  sI0 = *(const floatx4*)si; sI1 = *(const floatx4*)(si + 4); \
  sT = *(const half8*)(t_sc + ((size_t)rows0 + (ch) * 16 + srow) * 256 + scol); }
#define K2C_WRITE(ch) { char* bufw = smem + ((ch) & 1) * 16384; \
  half8 hi; \
  _Pragma("unroll") for (int j = 0; j < 4; ++j) { hi[j] = (_Float16)sI0[j]; hi[4+j] = (_Float16)sI1[j]; } \
  int o = srow * 1024 + ((scol * 2) ^ ssz); \
  *(half8*)(bufw + o) = hi; *(half8*)(bufw + o + 512) = sT; }

  K2C_LOAD(0); K2C_WRITE(0);
  __syncthreads();
#pragma unroll 1
  for (int ch = 0; ch < 4; ++ch) {
    if (ch < 3) K2C_LOAD(ch + 1);
    const char* buf = smem + (ch & 1) * 16384;
    floatx4 acc = {0.f, 0.f, 0.f, 0.f};
    const int base = lr * 1024, sz = (lr & 7) << 4;
#pragma unroll
    for (int ks = 0; ks < 16; ++ks) {   // ks>=8 = t half
      half8 a = *(const half8*)(buf + base + ((ks * 64 + lg * 16) ^ sz));
      acc = MFMA16(a, bw[ks], acc);
    }
#pragma unroll
    for (int j = 0; j < 4; ++j) {
      const size_t grow = (size_t)rows0 + ch * 16 + lg * 4 + j;
      float e2 = __expf(2.f * (acc[j] + bv));
      float cg = (e2 - 1.f) / (e2 + 1.f);
      float u = (float)u_sc[grow * 256 + c];
      float m = prev[grow * 256 + c];
      out0[grow * 256 + c] = (1.f - u) * m + u * cg;
    }
    if (ch < 3) K2C_WRITE(ch + 1);
    __syncthreads();
  }
}

// ---------------------------------------------------------------- K3a: attention row-sums (pass 1, no retention)
// grid (8, 32, 2) x 512. Block = 64 q-rows x 1024 keys (kh half). Wave w -> 128-key slice,
// all 4 q-groups (qf 64 VGPR). Swapped mfma(K,Q): acc row=key, col=q-row (lr).
// Partials -> part[b][kh][q] (f32) in the dead WQ/WK ws region.
__global__ __launch_bounds__(512, 4) void k3a_sums(
    const _Float16* __restrict__ ws, float* __restrict__ part)
{
  __shared__ float red[8][64];
  const int b = blockIdx.x, q0 = blockIdx.y * 64, kh = blockIdx.z;
  const int tid = threadIdx.x, w = tid >> 6, l = tid & 63;
  const int lr = l & 15, lg = l >> 4;

  const _Float16* Q  = ws + OFF_Q + ((size_t)b * 2048 + q0) * 128;
  const _Float16* Kp = ws + OFF_K + ((size_t)b * 2048 + kh * 1024 + w * 128) * 128;

  half8 qf[4][4];
#pragma unroll
  for (int qg = 0; qg < 4; ++qg)
#pragma unroll
    for (int ks = 0; ks < 4; ++ks)
      qf[qg][ks] = *(const half8*)(Q + (size_t)(qg * 16 + lr) * 128 + ks * 32 + lg * 8);

  float se[4] = {0.f, 0.f, 0.f, 0.f};
#pragma unroll 2
  for (int kt = 0; kt < 8; ++kt) {
    const _Float16* kp = Kp + (size_t)(kt * 16 + lr) * 128 + lg * 8;
    half8 kf[4];
#pragma unroll
    for (int ks = 0; ks < 4; ++ks) kf[ks] = *(const half8*)(kp + ks * 32);
#pragma unroll
    for (int qg = 0; qg < 4; ++qg) {
      floatx4 acc = {0.f, 0.f, 0.f, 0.f};
#pragma unroll
      for (int ks = 0; ks < 4; ++ks) acc = MFMA16(kf[ks], qf[qg][ks], acc);
#pragma unroll
      for (int j = 0; j < 4; ++j) se[qg] += __expf(acc[j] - 14.f);
    }
  }
#pragma unroll
  for (int qg = 0; qg < 4; ++qg) {
    se[qg] += __shfl_xor(se[qg], 16);
    se[qg] += __shfl_xor(se[qg], 32);
  }
  if (l < 16) {
#pragma unroll
    for (int qg = 0; qg < 4; ++qg) red[w][qg * 16 + l] = se[qg];
  }
  __syncthreads();
  if (tid < 64) {
    float t = 0.f;
#pragma unroll
    for (int ww = 0; ww < 8; ++ww) t += red[ww][tid];
    part[((size_t)b * 2 + kh) * 2048 + q0 + tid] = t;
  }
}

// ---------------------------------------------------------------- K3b: recompute + normalize + store (pass 2)
__global__ __launch_bounds__(512, 4) void k3b_store(
    const _Float16* __restrict__ ws, const float* __restrict__ part,
    float* __restrict__ out1)
{
  const int b = blockIdx.x, q0 = blockIdx.y * 64, kh = blockIdx.z;
  const int tid = threadIdx.x, w = tid >> 6, l = tid & 63;
  const int lr = l & 15, lg = l >> 4;

  const _Float16* Q  = ws + OFF_Q + ((size_t)b * 2048 + q0) * 128;
  const _Float16* Kp = ws + OFF_K + ((size_t)b * 2048 + kh * 1024 + w * 128) * 128;

  half8 qf[4][4];
  float inv[4];
#pragma unroll
  for (int qg = 0; qg < 4; ++qg) {
#pragma unroll
    for (int ks = 0; ks < 4; ++ks)
      qf[qg][ks] = *(const half8*)(Q + (size_t)(qg * 16 + lr) * 128 + ks * 32 + lg * 8);
    const int q = q0 + qg * 16 + lr;
    inv[qg] = 1.f / (part[(size_t)(b * 2 + 0) * 2048 + q] + part[(size_t)(b * 2 + 1) * 2048 + q]);
  }

#pragma unroll 2
  for (int kt = 0; kt < 8; ++kt) {
    const _Float16* kp = Kp + (size_t)(kt * 16 + lr) * 128 + lg * 8;
    half8 kf[4];
#pragma unroll
    for (int ks = 0; ks < 4; ++ks) kf[ks] = *(const half8*)(kp + ks * 32);
#pragma unroll
    for (int qg = 0; qg < 4; ++qg) {
      floatx4 acc = {0.f, 0.f, 0.f, 0.f};
#pragma unroll
      for (int ks = 0; ks < 4; ++ks) acc = MFMA16(kf[ks], qf[qg][ks], acc);
      floatx4 v;
#pragma unroll
      for (int j = 0; j < 4; ++j) v[j] = __expf(acc[j] - 14.f) * inv[qg];
      *(floatx4*)(out1 + ((size_t)b * 2048 + q0 + qg * 16 + lr) * 2048
                        + kh * 1024 + w * 128 + kt * 16 + lg * 4) = v;
    }
  }
}

// ----------------------------------------------------------------
extern "C" void kernel_launch(void* const* d_in, const int* in_sizes, int n_in,
                              void* d_out, int out_size, void* d_ws, size_t ws_size,
                              hipStream_t stream)
{
  const float* input = (const float*)d_in[0];
  const float* prev  = (const float*)d_in[1];
  const float* Wq = (const float*)d_in[2];
  const float* bq = (const float*)d_in[3];
  const float* Wk = (const float*)d_in[4];
  const float* bk = (const float*)d_in[5];
  const float* Wu = (const float*)d_in[8];
  const float* bu = (const float*)d_in[9];
  const float* Wr = (const float*)d_in[10];
  const float* br = (const float*)d_in[11];
  const float* Wc = (const float*)d_in[12];
  const float* bc = (const float*)d_in[13];

  float* out0 = (float*)d_out;                        // new_memory [8,2048,256]
  float* out1 = out0 + (size_t)8 * 2048 * 256;        // attention_probs [8,2048,2048]
  _Float16* ws = (_Float16*)d_ws;                     // 9,437,184 bytes used

  // t/u intermediates live in the out1 region (k3b overwrites it afterwards)
  _Float16* t_sc = (_Float16*)out1;                   // 4.19M halves
  _Float16* u_sc = (_Float16*)out1 + 4194304;         // 4.19M halves
  // softmax partial sums reuse the dead WQ/WK hi-lo region (k1 consumed it)
  float* part = (float*)ws;                           // 8*2*2048 f32 = 128 KB

  hipLaunchKernelGGL(k0_convert, dim3(1792), dim3(256), 0, stream, Wq, Wk, Wu, Wr, Wc, ws);
  hipLaunchKernelGGL(k1_proj,    dim3(256, 2), dim3(512), 0, stream, input, prev, bq, bk, ws);
  hipLaunchKernelGGL(k2ru,       dim3(128, 4), dim3(512), 0, stream, input, prev, br, bu, ws, t_sc, u_sc);
  hipLaunchKernelGGL(k2c,        dim3(256, 2), dim3(512), 0, stream, input, prev, bc, ws, t_sc, u_sc, out0);
  hipLaunchKernelGGL(k3a_sums,   dim3(8, 32, 2), dim3(512), 0, stream, ws, part);
  hipLaunchKernelGGL(k3b_store,  dim3(8, 32, 2), dim3(512), 0, stream, ws, part, out1);
}

// Round 11
// 110.525 us; speedup vs baseline: 2.9726x; 1.1673x over previous
//
#include <hip/hip_runtime.h>

// DynamicMemoryCell: B=8, N=2048, IN=256, MEM=256, CTX=128
// out0 = new_memory [8,2048,256] f32 ; out1 = attention_probs [8,2048,2048] f32
// Wv/value/context dead in reference -> skipped.
//
// R10: k3a/k3b with q-tile 128, waves split q (16 rows each, qf=16 VGPR),
// K staged through LDS (32 KB chunks, dbuf, pre-swizzled global src per T2/m173).
// K L2 traffic 256->128 MB; K consumed from LDS (~12cy) instead of L2 (~250cy).
// k0/k1/k2ru/k2c byte-identical to R9.

typedef _Float16 half8 __attribute__((ext_vector_type(8)));
typedef _Float16 half4 __attribute__((ext_vector_type(4)));
typedef float floatx4 __attribute__((ext_vector_type(4)));

#define MFMA16(a, b, c) __builtin_amdgcn_mfma_f32_16x16x32_f16((a), (b), (c), 0, 0, 0)

// ws layout (units: _Float16)
#define OFF_WQH 0
#define OFF_WQL 32768
#define OFF_WKH 65536
#define OFF_WKL 98304
#define OFF_WUH 131072
#define OFF_WRH 262144
#define OFF_WCH 393216
#define OFF_Q   524288
#define OFF_K   2621440
// total 4718592 halves = 9,437,184 bytes
// After k1, [OFF_WQH .. OFF_WUH) is dead -> f32 softmax partials (128 KB).

__device__ __forceinline__ void gload16(const void* g, void* l) {
  __builtin_amdgcn_global_load_lds((const __attribute__((address_space(1))) unsigned int*)g,
                                   (__attribute__((address_space(3))) unsigned int*)l, 16, 0, 0);
}

// ---------------------------------------------------------------- K0: weights fp32 -> fp16 (hi/lo for Wq/Wk)
__global__ __launch_bounds__(256) void k0_convert(
    const float* __restrict__ Wq, const float* __restrict__ Wk,
    const float* __restrict__ Wu, const float* __restrict__ Wr,
    const float* __restrict__ Wc, _Float16* __restrict__ ws)
{
  int i = blockIdx.x * 256 + threadIdx.x;
  if (i < 32768) {
    float w = Wq[i];
    _Float16 h = (_Float16)w;
    ws[OFF_WQH + i] = h;
    ws[OFF_WQL + i] = (_Float16)(w - (float)h);
  } else if (i < 65536) {
    int j = i - 32768;
    float w = Wk[j];
    _Float16 h = (_Float16)w;
    ws[OFF_WKH + j] = h;
    ws[OFF_WKL + j] = (_Float16)(w - (float)h);
  } else {
    int j = i - 65536;
    if (j < 131072)      ws[OFF_WUH + j]            = (_Float16)Wu[j];
    else if (j < 262144) ws[OFF_WRH + (j - 131072)] = (_Float16)Wr[j - 131072];
    else                 ws[OFF_WCH + (j - 262144)] = (_Float16)Wc[j - 262144];
  }
}

// ---------------------------------------------------------------- K1: Q/K projection (split-fp16, 3 products)
__global__ __launch_bounds__(512) void k1_proj(
    const float* __restrict__ input, const float* __restrict__ prev,
    const float* __restrict__ bq, const float* __restrict__ bk,
    _Float16* __restrict__ ws)
{
  __shared__ char smem[2 * 16384];   // 16 rows x [hi 512B | lo 512B]
  const int which = blockIdx.y;
  const float* x = which ? prev : input;
  const _Float16* WH = ws + (which ? OFF_WKH : OFF_WQH);
  const _Float16* WL = ws + (which ? OFF_WKL : OFF_WQL);
  const float* bias = which ? bk : bq;
  _Float16* out = ws + (which ? OFF_K : OFF_Q);

  const int tid = threadIdx.x, w = tid >> 6, l = tid & 63;
  const int lr = l & 15, lg = l >> 4;
  const int rows0 = blockIdx.x * 64;
  const int c = w * 16 + lr;

  half8 bh[8], blo[8];
#pragma unroll
  for (int ks = 0; ks < 8; ++ks) {
    bh[ks]  = *(const half8*)(WH + (size_t)c * 256 + ks * 32 + lg * 8);
    blo[ks] = *(const half8*)(WL + (size_t)c * 256 + ks * 32 + lg * 8);
  }
  const float bv = bias[c];

  const int srow = tid >> 5, scol = (tid & 31) * 8;
  const int ssz = (srow & 7) << 4;
  floatx4 st0, st1;

#define K1_LOAD(ch) { const float* src = x + ((size_t)rows0 + (ch) * 16 + srow) * 256 + scol; \
  st0 = *(const floatx4*)src; st1 = *(const floatx4*)(src + 4); }
#define K1_WRITE(ch) { char* bufw = smem + ((ch) & 1) * 16384; \
  half8 h, lo; \
  _Pragma("unroll") for (int j = 0; j < 4; ++j) { \
    h[j] = (_Float16)st0[j]; lo[j] = (_Float16)(st0[j] - (float)h[j]); \
    h[4+j] = (_Float16)st1[j]; lo[4+j] = (_Float16)(st1[j] - (float)h[4+j]); } \
  int o = srow * 1024 + ((scol * 2) ^ ssz); \
  *(half8*)(bufw + o) = h; *(half8*)(bufw + o + 512) = lo; }

  K1_LOAD(0); K1_WRITE(0);
  __syncthreads();
#pragma unroll 1
  for (int ch = 0; ch < 4; ++ch) {
    if (ch < 3) K1_LOAD(ch + 1);
    const char* buf = smem + (ch & 1) * 16384;
    floatx4 acc = {0.f, 0.f, 0.f, 0.f};
    const int base = lr * 1024, sz = (lr & 7) << 4;
#pragma unroll
    for (int ks = 0; ks < 8; ++ks) {
      int o = base + ((ks * 64 + lg * 16) ^ sz);
      half8 ah = *(const half8*)(buf + o);
      half8 al = *(const half8*)(buf + o + 512);
      acc = MFMA16(ah, bh[ks], acc);
      acc = MFMA16(al, bh[ks], acc);
      acc = MFMA16(ah, blo[ks], acc);
    }
#pragma unroll
    for (int j = 0; j < 4; ++j)
      out[((size_t)rows0 + ch * 16 + lg * 4 + j) * 128 + c] = (_Float16)(acc[j] + bv);
    if (ch < 3) K1_WRITE(ch + 1);
    __syncthreads();
  }
}

// ---------------------------------------------------------------- K2ru: reset + update fused via wave groups
__global__ __launch_bounds__(512) void k2ru(
    const float* __restrict__ input, const float* __restrict__ prev,
    const float* __restrict__ br, const float* __restrict__ bu,
    const _Float16* __restrict__ ws,
    _Float16* __restrict__ t_sc, _Float16* __restrict__ u_sc)
{
  __shared__ char smem[2 * 16384];   // 16 rows x [in 512B | prev 512B]
  const int tid = threadIdx.x, w = tid >> 6, l = tid & 63;
  const int lr = l & 15, lg = l >> 4;
  const int rows0 = blockIdx.x * 128;
  const int isU = w >> 2;
  const int c = blockIdx.y * 64 + (w & 3) * 16 + lr;

  const _Float16* W = ws + (isU ? OFF_WUH : OFF_WRH);
  half8 bw[16];
#pragma unroll
  for (int ks = 0; ks < 16; ++ks)
    bw[ks] = *(const half8*)(W + (size_t)c * 512 + ks * 32 + lg * 8);
  const float bv = (isU ? bu : br)[c];

  const int srow = tid >> 5, scol = (tid & 31) * 8;
  const int ssz = (srow & 7) << 4;
  floatx4 sI0, sI1, sP0, sP1;

#define K2RU_LOAD(ch) { \
  const float* si = input + ((size_t)rows0 + (ch) * 16 + srow) * 256 + scol; \
  const float* sp = prev  + ((size_t)rows0 + (ch) * 16 + srow) * 256 + scol; \
  sI0 = *(const floatx4*)si; sI1 = *(const floatx4*)(si + 4); \
  sP0 = *(const floatx4*)sp; sP1 = *(const floatx4*)(sp + 4); }
#define K2RU_WRITE(ch) { char* bufw = smem + ((ch) & 1) * 16384; \
  half8 hi, hp; \
  _Pragma("unroll") for (int j = 0; j < 4; ++j) { \
    hi[j] = (_Float16)sI0[j]; hi[4+j] = (_Float16)sI1[j]; \
    hp[j] = (_Float16)sP0[j]; hp[4+j] = (_Float16)sP1[j]; } \
  int o = srow * 1024 + ((scol * 2) ^ ssz); \
  *(half8*)(bufw + o) = hi; *(half8*)(bufw + o + 512) = hp; }

  K2RU_LOAD(0); K2RU_WRITE(0);
  __syncthreads();
#pragma unroll 1
  for (int ch = 0; ch < 8; ++ch) {
    if (ch < 7) K2RU_LOAD(ch + 1);
    const char* buf = smem + (ch & 1) * 16384;
    floatx4 acc = {0.f, 0.f, 0.f, 0.f};
    const int base = lr * 1024, sz = (lr & 7) << 4;
#pragma unroll
    for (int ks = 0; ks < 16; ++ks) {   // ks>=8 lands in [512,1024) = prev half
      half8 a = *(const half8*)(buf + base + ((ks * 64 + lg * 16) ^ sz));
      acc = MFMA16(a, bw[ks], acc);
    }
#pragma unroll
    for (int j = 0; j < 4; ++j) {
      const int crow = lg * 4 + j;
      const size_t grow = (size_t)rows0 + ch * 16 + crow;
      float g = 1.f / (1.f + __expf(-(acc[j] + bv)));
      if (!isU) {
        float m = (float)*(const _Float16*)(buf + crow * 1024 + 512 + ((c * 2) ^ ((crow & 7) << 4)));
        t_sc[grow * 256 + c] = (_Float16)(g * m);
      } else {
        u_sc[grow * 256 + c] = (_Float16)g;
      }
    }
    if (ch < 7) K2RU_WRITE(ch + 1);
    __syncthreads();
  }
}

// ---------------------------------------------------------------- K2c: candidate + combine -> out0
__global__ __launch_bounds__(512) void k2c(
    const float* __restrict__ input, const float* __restrict__ prev,
    const float* __restrict__ bc, const _Float16* __restrict__ ws,
    const _Float16* __restrict__ t_sc, const _Float16* __restrict__ u_sc,
    float* __restrict__ out0)
{
  __shared__ char smem[2 * 16384];   // 16 rows x [in 512B | t 512B]
  const int tid = threadIdx.x, w = tid >> 6, l = tid & 63;
  const int lr = l & 15, lg = l >> 4;
  const int rows0 = blockIdx.x * 64;
  const int c = blockIdx.y * 128 + w * 16 + lr;

  half8 bw[16];
#pragma unroll
  for (int ks = 0; ks < 16; ++ks)
    bw[ks] = *(const half8*)(ws + OFF_WCH + (size_t)c * 512 + ks * 32 + lg * 8);
  const float bv = bc[c];

  const int srow = tid >> 5, scol = (tid & 31) * 8;
  const int ssz = (srow & 7) << 4;
  floatx4 sI0, sI1;
  half8 sT;

#define K2C_LOAD(ch) { \
  const float* si = input + ((size_t)rows0 + (ch) * 16 + srow) * 256 + scol; \
  sI0 = *(const floatx4*)si; sI1 = *(const floatx4*)(si + 4); \
  sT = *(const half8*)(t_sc + ((size_t)rows0 + (ch) * 16 + srow) * 256 + scol); }
#define K2C_WRITE(ch) { char* bufw = smem + ((ch) & 1) * 16384; \
  half8 hi; \
  _Pragma("unroll") for (int j = 0; j < 4; ++j) { hi[j] = (_Float16)sI0[j]; hi[4+j] = (_Float16)sI1[j]; } \
  int o = srow * 1024 + ((scol * 2) ^ ssz); \
  *(half8*)(bufw + o) = hi; *(half8*)(bufw + o + 512) = sT; }

  K2C_LOAD(0); K2C_WRITE(0);
  __syncthreads();
#pragma unroll 1
  for (int ch = 0; ch < 4; ++ch) {
    if (ch < 3) K2C_LOAD(ch + 1);
    const char* buf = smem + (ch & 1) * 16384;
    floatx4 acc = {0.f, 0.f, 0.f, 0.f};
    const int base = lr * 1024, sz = (lr & 7) << 4;
#pragma unroll
    for (int ks = 0; ks < 16; ++ks) {   // ks>=8 = t half
      half8 a = *(const half8*)(buf + base + ((ks * 64 + lg * 16) ^ sz));
      acc = MFMA16(a, bw[ks], acc);
    }
#pragma unroll
    for (int j = 0; j < 4; ++j) {
      const size_t grow = (size_t)rows0 + ch * 16 + lg * 4 + j;
      float e2 = __expf(2.f * (acc[j] + bv));
      float cg = (e2 - 1.f) / (e2 + 1.f);
      float u = (float)u_sc[grow * 256 + c];
      float m = prev[grow * 256 + c];
      out0[grow * 256 + c] = (1.f - u) * m + u * cg;
    }
    if (ch < 3) K2C_WRITE(ch + 1);
    __syncthreads();
  }
}

// ---------------------------------------------------------------- K3 common staging
// Chunk = 128 keys x 256 B = 32 KB. LDS dest linear (gload_lds); global source
// pre-swizzled with col ^ ((row&7)<<4) so swizzled ds_read is conflict-free.
#define K3_STAGE(Kg, dst, ch) { \
  const char* g_ = (Kg) + (ch) * 32768; \
  _Pragma("unroll") for (int i_ = 0; i_ < 4; ++i_) { \
    int o_ = w * 1024 + i_ * 8192 + l * 16; \
    int row_ = o_ >> 8, col_ = o_ & 255; \
    gload16(g_ + row_ * 256 + (col_ ^ ((row_ & 7) << 4)), (dst) + w * 1024 + i_ * 8192); } }

// ---------------------------------------------------------------- K3a: softmax row-sums (pass 1)
// grid (8, 16, 2) x 512. Block = 128 q-rows x 1024 keys (kh half). 8 waves split q (16 rows).
// K staged via LDS dbuf. Swapped mfma(K,Q): acc reg j = key lg*4+j, lane col lr = q-row.
__global__ __launch_bounds__(512) void k3a_sums(
    const _Float16* __restrict__ ws, float* __restrict__ part)
{
  __shared__ char kbuf[2][32768];
  const int b = blockIdx.x, q0 = blockIdx.y * 128, kh = blockIdx.z;
  const int tid = threadIdx.x, w = tid >> 6, l = tid & 63;
  const int lr = l & 15, lg = l >> 4;

  const _Float16* Q = ws + OFF_Q + ((size_t)b * 2048 + q0 + w * 16) * 128;
  const char* Kg = (const char*)(ws + OFF_K + ((size_t)b * 2048 + kh * 1024) * 128);

  half8 qf[4];
#pragma unroll
  for (int ks = 0; ks < 4; ++ks)
    qf[ks] = *(const half8*)(Q + (size_t)lr * 128 + ks * 32 + lg * 8);

  K3_STAGE(Kg, kbuf[0], 0);
  __syncthreads();

  float se = 0.f;
#pragma unroll 1
  for (int ch = 0; ch < 8; ++ch) {
    if (ch < 7) K3_STAGE(Kg, kbuf[(ch + 1) & 1], ch + 1);
    const char* buf = kbuf[ch & 1];
#pragma unroll
    for (int kt = 0; kt < 8; ++kt) {
      const int kk = kt * 16 + lr;
      const int kbase = kk * 256, ksz = (kk & 7) << 4;
      half8 kf[4];
#pragma unroll
      for (int ks = 0; ks < 4; ++ks)
        kf[ks] = *(const half8*)(buf + kbase + ((ks * 64 + lg * 16) ^ ksz));
      floatx4 acc = {0.f, 0.f, 0.f, 0.f};
#pragma unroll
      for (int ks = 0; ks < 4; ++ks) acc = MFMA16(kf[ks], qf[ks], acc);
#pragma unroll
      for (int j = 0; j < 4; ++j) se += __expf(acc[j] - 14.f);
    }
    __syncthreads();
  }
  // reduce over lg (lanes sharing a q-row); waves own distinct q-rows -> no cross-wave reduce
  se += __shfl_xor(se, 16);
  se += __shfl_xor(se, 32);
  if (lg == 0)
    part[((size_t)b * 2 + kh) * 2048 + q0 + w * 16 + lr] = se;
}

// ---------------------------------------------------------------- K3b: recompute + normalize + store (pass 2)
__global__ __launch_bounds__(512) void k3b_store(
    const _Float16* __restrict__ ws, const float* __restrict__ part,
    float* __restrict__ out1)
{
  __shared__ char kbuf[2][32768];
  const int b = blockIdx.x, q0 = blockIdx.y * 128, kh = blockIdx.z;
  const int tid = threadIdx.x, w = tid >> 6, l = tid & 63;
  const int lr = l & 15, lg = l >> 4;

  const int q = q0 + w * 16 + lr;
  const _Float16* Q = ws + OFF_Q + ((size_t)b * 2048 + q0 + w * 16) * 128;
  const char* Kg = (const char*)(ws + OFF_K + ((size_t)b * 2048 + kh * 1024) * 128);

  half8 qf[4];
#pragma unroll
  for (int ks = 0; ks < 4; ++ks)
    qf[ks] = *(const half8*)(Q + (size_t)lr * 128 + ks * 32 + lg * 8);
  const float inv = 1.f / (part[(size_t)(b * 2 + 0) * 2048 + q] +
                           part[(size_t)(b * 2 + 1) * 2048 + q]);

  K3_STAGE(Kg, kbuf[0], 0);
  __syncthreads();

  float* orow = out1 + ((size_t)b * 2048 + q) * 2048 + kh * 1024;
#pragma unroll 1
  for (int ch = 0; ch < 8; ++ch) {
    if (ch < 7) K3_STAGE(Kg, kbuf[(ch + 1) & 1], ch + 1);
    const char* buf = kbuf[ch & 1];
#pragma unroll
    for (int kt = 0; kt < 8; ++kt) {
      const int kk = kt * 16 + lr;
      const int kbase = kk * 256, ksz = (kk & 7) << 4;
      half8 kf[4];
#pragma unroll
      for (int ks = 0; ks < 4; ++ks)
        kf[ks] = *(const half8*)(buf + kbase + ((ks * 64 + lg * 16) ^ ksz));
      floatx4 acc = {0.f, 0.f, 0.f, 0.f};
#pragma unroll
      for (int ks = 0; ks < 4; ++ks) acc = MFMA16(kf[ks], qf[ks], acc);
      floatx4 v;
#pragma unroll
      for (int j = 0; j < 4; ++j) v[j] = __expf(acc[j] - 14.f) * inv;
      *(floatx4*)(orow + ch * 128 + kt * 16 + lg * 4) = v;
    }
    __syncthreads();
  }
}

// ----------------------------------------------------------------
extern "C" void kernel_launch(void* const* d_in, const int* in_sizes, int n_in,
                              void* d_out, int out_size, void* d_ws, size_t ws_size,
                              hipStream_t stream)
{
  const float* input = (const float*)d_in[0];
  const float* prev  = (const float*)d_in[1];
  const float* Wq = (const float*)d_in[2];
  const float* bq = (const float*)d_in[3];
  const float* Wk = (const float*)d_in[4];
  const float* bk = (const float*)d_in[5];
  const float* Wu = (const float*)d_in[8];
  const float* bu = (const float*)d_in[9];
  const float* Wr = (const float*)d_in[10];
  const float* br = (const float*)d_in[11];
  const float* Wc = (const float*)d_in[12];
  const float* bc = (const float*)d_in[13];

  float* out0 = (float*)d_out;                        // new_memory [8,2048,256]
  float* out1 = out0 + (size_t)8 * 2048 * 256;        // attention_probs [8,2048,2048]
  _Float16* ws = (_Float16*)d_ws;                     // 9,437,184 bytes used

  // t/u intermediates live in the out1 region (k3b overwrites it afterwards)
  _Float16* t_sc = (_Float16*)out1;                   // 4.19M halves
  _Float16* u_sc = (_Float16*)out1 + 4194304;         // 4.19M halves
  // softmax partial sums reuse the dead WQ/WK hi-lo region (k1 consumed it)
  float* part = (float*)ws;                           // 8*2*2048 f32 = 128 KB

  hipLaunchKernelGGL(k0_convert, dim3(1792), dim3(256), 0, stream, Wq, Wk, Wu, Wr, Wc, ws);
  hipLaunchKernelGGL(k1_proj,    dim3(256, 2), dim3(512), 0, stream, input, prev, bq, bk, ws);
  hipLaunchKernelGGL(k2ru,       dim3(128, 4), dim3(512), 0, stream, input, prev, br, bu, ws, t_sc, u_sc);
  hipLaunchKernelGGL(k2c,        dim3(256, 2), dim3(512), 0, stream, input, prev, bc, ws, t_sc, u_sc, out0);
  hipLaunchKernelGGL(k3a_sums,   dim3(8, 16, 2), dim3(512), 0, stream, ws, part);
  hipLaunchKernelGGL(k3b_store,  dim3(8, 16, 2), dim3(512), 0, stream, ws, part, out1);
}

// Round 12
// 109.479 us; speedup vs baseline: 3.0010x; 1.0096x over previous
//
#include <hip/hip_runtime.h>

// DynamicMemoryCell: B=8, N=2048, IN=256, MEM=256, CTX=128
// out0 = new_memory [8,2048,256] f32 ; out1 = attention_probs [8,2048,2048] f32
// Wv/value/context dead in reference -> skipped.
//
// R11: (1) k3a/k3b key-split 2->4 (512 blocks each, 2/CU, 4-chunk serial chain);
//      (2) k1 drops to 2 MFMA products (W exact via hi/lo, x fp16) + hi-only staging.
// k0/k2ru/k2c byte-identical to R10.

typedef _Float16 half8 __attribute__((ext_vector_type(8)));
typedef _Float16 half4 __attribute__((ext_vector_type(4)));
typedef float floatx4 __attribute__((ext_vector_type(4)));

#define MFMA16(a, b, c) __builtin_amdgcn_mfma_f32_16x16x32_f16((a), (b), (c), 0, 0, 0)

// ws layout (units: _Float16)
#define OFF_WQH 0
#define OFF_WQL 32768
#define OFF_WKH 65536
#define OFF_WKL 98304
#define OFF_WUH 131072
#define OFF_WRH 262144
#define OFF_WCH 393216
#define OFF_Q   524288
#define OFF_K   2621440
// total 4718592 halves = 9,437,184 bytes
// After k1, [OFF_WQH .. OFF_WUH) is dead -> f32 softmax partials 8*4*2048*4B = 256 KB (exact fit).

__device__ __forceinline__ void gload16(const void* g, void* l) {
  __builtin_amdgcn_global_load_lds((const __attribute__((address_space(1))) unsigned int*)g,
                                   (__attribute__((address_space(3))) unsigned int*)l, 16, 0, 0);
}

// ---------------------------------------------------------------- K0: weights fp32 -> fp16 (hi/lo for Wq/Wk)
__global__ __launch_bounds__(256) void k0_convert(
    const float* __restrict__ Wq, const float* __restrict__ Wk,
    const float* __restrict__ Wu, const float* __restrict__ Wr,
    const float* __restrict__ Wc, _Float16* __restrict__ ws)
{
  int i = blockIdx.x * 256 + threadIdx.x;
  if (i < 32768) {
    float w = Wq[i];
    _Float16 h = (_Float16)w;
    ws[OFF_WQH + i] = h;
    ws[OFF_WQL + i] = (_Float16)(w - (float)h);
  } else if (i < 65536) {
    int j = i - 32768;
    float w = Wk[j];
    _Float16 h = (_Float16)w;
    ws[OFF_WKH + j] = h;
    ws[OFF_WKL + j] = (_Float16)(w - (float)h);
  } else {
    int j = i - 65536;
    if (j < 131072)      ws[OFF_WUH + j]            = (_Float16)Wu[j];
    else if (j < 262144) ws[OFF_WRH + (j - 131072)] = (_Float16)Wr[j - 131072];
    else                 ws[OFF_WCH + (j - 262144)] = (_Float16)Wc[j - 262144];
  }
}

// ---------------------------------------------------------------- K1: Q/K projection (2 products: W hi/lo, x fp16)
// grid (256, 2) x 512. x: 64-row block, y: 0=Q(input,Wq) 1=K(prev,Wk).
// 8 waves x 16 cols. A (x fp16, hi only) staged in 16-row chunks (2x8 KB LDS).
__global__ __launch_bounds__(512) void k1_proj(
    const float* __restrict__ input, const float* __restrict__ prev,
    const float* __restrict__ bq, const float* __restrict__ bk,
    _Float16* __restrict__ ws)
{
  __shared__ char smem[2 * 8192];   // 16 rows x 512B (x fp16)
  const int which = blockIdx.y;
  const float* x = which ? prev : input;
  const _Float16* WH = ws + (which ? OFF_WKH : OFF_WQH);
  const _Float16* WL = ws + (which ? OFF_WKL : OFF_WQL);
  const float* bias = which ? bk : bq;
  _Float16* out = ws + (which ? OFF_K : OFF_Q);

  const int tid = threadIdx.x, w = tid >> 6, l = tid & 63;
  const int lr = l & 15, lg = l >> 4;
  const int rows0 = blockIdx.x * 64;
  const int c = w * 16 + lr;

  half8 bh[8], blo[8];
#pragma unroll
  for (int ks = 0; ks < 8; ++ks) {
    bh[ks]  = *(const half8*)(WH + (size_t)c * 256 + ks * 32 + lg * 8);
    blo[ks] = *(const half8*)(WL + (size_t)c * 256 + ks * 32 + lg * 8);
  }
  const float bv = bias[c];

  const int srow = tid >> 5, scol = (tid & 31) * 8;
  const int ssz = (srow & 7) << 4;
  floatx4 st0, st1;

#define K1_LOAD(ch) { const float* src = x + ((size_t)rows0 + (ch) * 16 + srow) * 256 + scol; \
  st0 = *(const floatx4*)src; st1 = *(const floatx4*)(src + 4); }
#define K1_WRITE(ch) { char* bufw = smem + ((ch) & 1) * 8192; \
  half8 h; \
  _Pragma("unroll") for (int j = 0; j < 4; ++j) { \
    h[j] = (_Float16)st0[j]; h[4+j] = (_Float16)st1[j]; } \
  *(half8*)(bufw + srow * 512 + ((scol * 2) ^ ssz)) = h; }

  K1_LOAD(0); K1_WRITE(0);
  __syncthreads();
#pragma unroll 1
  for (int ch = 0; ch < 4; ++ch) {
    if (ch < 3) K1_LOAD(ch + 1);
    const char* buf = smem + (ch & 1) * 8192;
    floatx4 acc = {0.f, 0.f, 0.f, 0.f};
    const int base = lr * 512, sz = (lr & 7) << 4;
#pragma unroll
    for (int ks = 0; ks < 8; ++ks) {
      half8 ah = *(const half8*)(buf + base + ((ks * 64 + lg * 16) ^ sz));
      acc = MFMA16(ah, bh[ks], acc);
      acc = MFMA16(ah, blo[ks], acc);
    }
#pragma unroll
    for (int j = 0; j < 4; ++j)
      out[((size_t)rows0 + ch * 16 + lg * 4 + j) * 128 + c] = (_Float16)(acc[j] + bv);
    if (ch < 3) K1_WRITE(ch + 1);
    __syncthreads();
  }
}

// ---------------------------------------------------------------- K2ru: reset + update fused via wave groups
__global__ __launch_bounds__(512) void k2ru(
    const float* __restrict__ input, const float* __restrict__ prev,
    const float* __restrict__ br, const float* __restrict__ bu,
    const _Float16* __restrict__ ws,
    _Float16* __restrict__ t_sc, _Float16* __restrict__ u_sc)
{
  __shared__ char smem[2 * 16384];   // 16 rows x [in 512B | prev 512B]
  const int tid = threadIdx.x, w = tid >> 6, l = tid & 63;
  const int lr = l & 15, lg = l >> 4;
  const int rows0 = blockIdx.x * 128;
  const int isU = w >> 2;
  const int c = blockIdx.y * 64 + (w & 3) * 16 + lr;

  const _Float16* W = ws + (isU ? OFF_WUH : OFF_WRH);
  half8 bw[16];
#pragma unroll
  for (int ks = 0; ks < 16; ++ks)
    bw[ks] = *(const half8*)(W + (size_t)c * 512 + ks * 32 + lg * 8);
  const float bv = (isU ? bu : br)[c];

  const int srow = tid >> 5, scol = (tid & 31) * 8;
  const int ssz = (srow & 7) << 4;
  floatx4 sI0, sI1, sP0, sP1;

#define K2RU_LOAD(ch) { \
  const float* si = input + ((size_t)rows0 + (ch) * 16 + srow) * 256 + scol; \
  const float* sp = prev  + ((size_t)rows0 + (ch) * 16 + srow) * 256 + scol; \
  sI0 = *(const floatx4*)si; sI1 = *(const floatx4*)(si + 4); \
  sP0 = *(const floatx4*)sp; sP1 = *(const floatx4*)(sp + 4); }
#define K2RU_WRITE(ch) { char* bufw = smem + ((ch) & 1) * 16384; \
  half8 hi, hp; \
  _Pragma("unroll") for (int j = 0; j < 4; ++j) { \
    hi[j] = (_Float16)sI0[j]; hi[4+j] = (_Float16)sI1[j]; \
    hp[j] = (_Float16)sP0[j]; hp[4+j] = (_Float16)sP1[j]; } \
  int o = srow * 1024 + ((scol * 2) ^ ssz); \
  *(half8*)(bufw + o) = hi; *(half8*)(bufw + o + 512) = hp; }

  K2RU_LOAD(0); K2RU_WRITE(0);
  __syncthreads();
#pragma unroll 1
  for (int ch = 0; ch < 8; ++ch) {
    if (ch < 7) K2RU_LOAD(ch + 1);
    const char* buf = smem + (ch & 1) * 16384;
    floatx4 acc = {0.f, 0.f, 0.f, 0.f};
    const int base = lr * 1024, sz = (lr & 7) << 4;
#pragma unroll
    for (int ks = 0; ks < 16; ++ks) {   // ks>=8 lands in [512,1024) = prev half
      half8 a = *(const half8*)(buf + base + ((ks * 64 + lg * 16) ^ sz));
      acc = MFMA16(a, bw[ks], acc);
    }
#pragma unroll
    for (int j = 0; j < 4; ++j) {
      const int crow = lg * 4 + j;
      const size_t grow = (size_t)rows0 + ch * 16 + crow;
      float g = 1.f / (1.f + __expf(-(acc[j] + bv)));
      if (!isU) {
        float m = (float)*(const _Float16*)(buf + crow * 1024 + 512 + ((c * 2) ^ ((crow & 7) << 4)));
        t_sc[grow * 256 + c] = (_Float16)(g * m);
      } else {
        u_sc[grow * 256 + c] = (_Float16)g;
      }
    }
    if (ch < 7) K2RU_WRITE(ch + 1);
    __syncthreads();
  }
}

// ---------------------------------------------------------------- K2c: candidate + combine -> out0
__global__ __launch_bounds__(512) void k2c(
    const float* __restrict__ input, const float* __restrict__ prev,
    const float* __restrict__ bc, const _Float16* __restrict__ ws,
    const _Float16* __restrict__ t_sc, const _Float16* __restrict__ u_sc,
    float* __restrict__ out0)
{
  __shared__ char smem[2 * 16384];   // 16 rows x [in 512B | t 512B]
  const int tid = threadIdx.x, w = tid >> 6, l = tid & 63;
  const int lr = l & 15, lg = l >> 4;
  const int rows0 = blockIdx.x * 64;
  const int c = blockIdx.y * 128 + w * 16 + lr;

  half8 bw[16];
#pragma unroll
  for (int ks = 0; ks < 16; ++ks)
    bw[ks] = *(const half8*)(ws + OFF_WCH + (size_t)c * 512 + ks * 32 + lg * 8);
  const float bv = bc[c];

  const int srow = tid >> 5, scol = (tid & 31) * 8;
  const int ssz = (srow & 7) << 4;
  floatx4 sI0, sI1;
  half8 sT;

#define K2C_LOAD(ch) { \
  const float* si = input + ((size_t)rows0 + (ch) * 16 + srow) * 256 + scol; \
  sI0 = *(const floatx4*)si; sI1 = *(const floatx4*)(si + 4); \
  sT = *(const half8*)(t_sc + ((size_t)rows0 + (ch) * 16 + srow) * 256 + scol); }
#define K2C_WRITE(ch) { char* bufw = smem + ((ch) & 1) * 16384; \
  half8 hi; \
  _Pragma("unroll") for (int j = 0; j < 4; ++j) { hi[j] = (_Float16)sI0[j]; hi[4+j] = (_Float16)sI1[j]; } \
  int o = srow * 1024 + ((scol * 2) ^ ssz); \
  *(half8*)(bufw + o) = hi; *(half8*)(bufw + o + 512) = sT; }

  K2C_LOAD(0); K2C_WRITE(0);
  __syncthreads();
#pragma unroll 1
  for (int ch = 0; ch < 4; ++ch) {
    if (ch < 3) K2C_LOAD(ch + 1);
    const char* buf = smem + (ch & 1) * 16384;
    floatx4 acc = {0.f, 0.f, 0.f, 0.f};
    const int base = lr * 1024, sz = (lr & 7) << 4;
#pragma unroll
    for (int ks = 0; ks < 16; ++ks) {   // ks>=8 = t half
      half8 a = *(const half8*)(buf + base + ((ks * 64 + lg * 16) ^ sz));
      acc = MFMA16(a, bw[ks], acc);
    }
#pragma unroll
    for (int j = 0; j < 4; ++j) {
      const size_t grow = (size_t)rows0 + ch * 16 + lg * 4 + j;
      float e2 = __expf(2.f * (acc[j] + bv));
      float cg = (e2 - 1.f) / (e2 + 1.f);
      float u = (float)u_sc[grow * 256 + c];
      float m = prev[grow * 256 + c];
      out0[grow * 256 + c] = (1.f - u) * m + u * cg;
    }
    if (ch < 3) K2C_WRITE(ch + 1);
    __syncthreads();
  }
}

// ---------------------------------------------------------------- K3 common staging
// Chunk = 128 keys x 256 B = 32 KB. LDS dest linear (gload_lds); global source
// pre-swizzled with col ^ ((row&7)<<4) so swizzled ds_read is conflict-free.
#define K3_STAGE(Kg, dst, ch) { \
  const char* g_ = (Kg) + (ch) * 32768; \
  _Pragma("unroll") for (int i_ = 0; i_ < 4; ++i_) { \
    int o_ = w * 1024 + i_ * 8192 + l * 16; \
    int row_ = o_ >> 8, col_ = o_ & 255; \
    gload16(g_ + row_ * 256 + (col_ ^ ((row_ & 7) << 4)), (dst) + w * 1024 + i_ * 8192); } }

// ---------------------------------------------------------------- K3a: softmax row-sums (pass 1)
// grid (8, 16, 4) x 512. Block = 128 q-rows x 512 keys (kh quarter). 8 waves split q (16 rows).
// K staged via LDS dbuf (4 chunks). Swapped mfma(K,Q): acc reg j = key lg*4+j, col lr = q-row.
__global__ __launch_bounds__(512) void k3a_sums(
    const _Float16* __restrict__ ws, float* __restrict__ part)
{
  __shared__ char kbuf[2][32768];
  const int b = blockIdx.x, q0 = blockIdx.y * 128, kh = blockIdx.z;
  const int tid = threadIdx.x, w = tid >> 6, l = tid & 63;
  const int lr = l & 15, lg = l >> 4;

  const _Float16* Q = ws + OFF_Q + ((size_t)b * 2048 + q0 + w * 16) * 128;
  const char* Kg = (const char*)(ws + OFF_K + ((size_t)b * 2048 + kh * 512) * 128);

  half8 qf[4];
#pragma unroll
  for (int ks = 0; ks < 4; ++ks)
    qf[ks] = *(const half8*)(Q + (size_t)lr * 128 + ks * 32 + lg * 8);

  K3_STAGE(Kg, kbuf[0], 0);
  __syncthreads();

  float se = 0.f;
#pragma unroll 1
  for (int ch = 0; ch < 4; ++ch) {
    if (ch < 3) K3_STAGE(Kg, kbuf[(ch + 1) & 1], ch + 1);
    const char* buf = kbuf[ch & 1];
#pragma unroll
    for (int kt = 0; kt < 8; ++kt) {
      const int kk = kt * 16 + lr;
      const int kbase = kk * 256, ksz = (kk & 7) << 4;
      half8 kf[4];
#pragma unroll
      for (int ks = 0; ks < 4; ++ks)
        kf[ks] = *(const half8*)(buf + kbase + ((ks * 64 + lg * 16) ^ ksz));
      floatx4 acc = {0.f, 0.f, 0.f, 0.f};
#pragma unroll
      for (int ks = 0; ks < 4; ++ks) acc = MFMA16(kf[ks], qf[ks], acc);
#pragma unroll
      for (int j = 0; j < 4; ++j) se += __expf(acc[j] - 14.f);
    }
    __syncthreads();
  }
  // reduce over lg (lanes sharing a q-row); waves own distinct q-rows -> no cross-wave reduce
  se += __shfl_xor(se, 16);
  se += __shfl_xor(se, 32);
  if (lg == 0)
    part[((size_t)b * 4 + kh) * 2048 + q0 + w * 16 + lr] = se;
}

// ---------------------------------------------------------------- K3b: recompute + normalize + store (pass 2)
// grid (8, 16, 4) x 512. Same geometry as k3a; denominator = sum of 4 partials.
__global__ __launch_bounds__(512) void k3b_store(
    const _Float16* __restrict__ ws, const float* __restrict__ part,
    float* __restrict__ out1)
{
  __shared__ char kbuf[2][32768];
  const int b = blockIdx.x, q0 = blockIdx.y * 128, kh = blockIdx.z;
  const int tid = threadIdx.x, w = tid >> 6, l = tid & 63;
  const int lr = l & 15, lg = l >> 4;

  const int q = q0 + w * 16 + lr;
  const _Float16* Q = ws + OFF_Q + ((size_t)b * 2048 + q0 + w * 16) * 128;
  const char* Kg = (const char*)(ws + OFF_K + ((size_t)b * 2048 + kh * 512) * 128);

  half8 qf[4];
#pragma unroll
  for (int ks = 0; ks < 4; ++ks)
    qf[ks] = *(const half8*)(Q + (size_t)lr * 128 + ks * 32 + lg * 8);
  const float inv = 1.f / (part[(size_t)(b * 4 + 0) * 2048 + q] +
                           part[(size_t)(b * 4 + 1) * 2048 + q] +
                           part[(size_t)(b * 4 + 2) * 2048 + q] +
                           part[(size_t)(b * 4 + 3) * 2048 + q]);

  K3_STAGE(Kg, kbuf[0], 0);
  __syncthreads();

  float* orow = out1 + ((size_t)b * 2048 + q) * 2048 + kh * 512;
#pragma unroll 1
  for (int ch = 0; ch < 4; ++ch) {
    if (ch < 3) K3_STAGE(Kg, kbuf[(ch + 1) & 1], ch + 1);
    const char* buf = kbuf[ch & 1];
#pragma unroll
    for (int kt = 0; kt < 8; ++kt) {
      const int kk = kt * 16 + lr;
      const int kbase = kk * 256, ksz = (kk & 7) << 4;
      half8 kf[4];
#pragma unroll
      for (int ks = 0; ks < 4; ++ks)
        kf[ks] = *(const half8*)(buf + kbase + ((ks * 64 + lg * 16) ^ ksz));
      floatx4 acc = {0.f, 0.f, 0.f, 0.f};
#pragma unroll
      for (int ks = 0; ks < 4; ++ks) acc = MFMA16(kf[ks], qf[ks], acc);
      floatx4 v;
#pragma unroll
      for (int j = 0; j < 4; ++j) v[j] = __expf(acc[j] - 14.f) * inv;
      *(floatx4*)(orow + ch * 128 + kt * 16 + lg * 4) = v;
    }
    __syncthreads();
  }
}

// ----------------------------------------------------------------
extern "C" void kernel_launch(void* const* d_in, const int* in_sizes, int n_in,
                              void* d_out, int out_size, void* d_ws, size_t ws_size,
                              hipStream_t stream)
{
  const float* input = (const float*)d_in[0];
  const float* prev  = (const float*)d_in[1];
  const float* Wq = (const float*)d_in[2];
  const float* bq = (const float*)d_in[3];
  const float* Wk = (const float*)d_in[4];
  const float* bk = (const float*)d_in[5];
  const float* Wu = (const float*)d_in[8];
  const float* bu = (const float*)d_in[9];
  const float* Wr = (const float*)d_in[10];
  const float* br = (const float*)d_in[11];
  const float* Wc = (const float*)d_in[12];
  const float* bc = (const float*)d_in[13];

  float* out0 = (float*)d_out;                        // new_memory [8,2048,256]
  float* out1 = out0 + (size_t)8 * 2048 * 256;        // attention_probs [8,2048,2048]
  _Float16* ws = (_Float16*)d_ws;                     // 9,437,184 bytes used

  // t/u intermediates live in the out1 region (k3b overwrites it afterwards)
  _Float16* t_sc = (_Float16*)out1;                   // 4.19M halves
  _Float16* u_sc = (_Float16*)out1 + 4194304;         // 4.19M halves
  // softmax partial sums reuse the dead WQ/WK hi-lo region (k1 consumed it): 256 KB
  float* part = (float*)ws;

  hipLaunchKernelGGL(k0_convert, dim3(1792), dim3(256), 0, stream, Wq, Wk, Wu, Wr, Wc, ws);
  hipLaunchKernelGGL(k1_proj,    dim3(256, 2), dim3(512), 0, stream, input, prev, bq, bk, ws);
  hipLaunchKernelGGL(k2ru,       dim3(128, 4), dim3(512), 0, stream, input, prev, br, bu, ws, t_sc, u_sc);
  hipLaunchKernelGGL(k2c,        dim3(256, 2), dim3(512), 0, stream, input, prev, bc, ws, t_sc, u_sc, out0);
  hipLaunchKernelGGL(k3a_sums,   dim3(8, 16, 4), dim3(512), 0, stream, ws, part);
  hipLaunchKernelGGL(k3b_store,  dim3(8, 16, 4), dim3(512), 0, stream, ws, part, out1);
}